// Round 11
// baseline (768.460 us; speedup 1.0000x reference)
//
#include <hip/hip_runtime.h>
#include <cstdint>
#include <cstddef>

// ---------------------------------------------------------------------------
// Shapes: x (2,8,96,96,192) fp32 ; windows 1x8x8 ; NH=2 ; hd=96 ; L=512 ; MLP 768
// tokens N = 147456 ; Bp = 288 ; Dn = 8
// ---------------------------------------------------------------------------

typedef float   f32x4  __attribute__((ext_vector_type(4)));
typedef __bf16  bf16x8 __attribute__((ext_vector_type(8)));
typedef unsigned int   u32x4  __attribute__((ext_vector_type(4)));
typedef unsigned short u16x4  __attribute__((ext_vector_type(4)));

#define DEVI __device__ __forceinline__

DEVI float bf2f(unsigned short u) {
    union { unsigned int i; float f; } v; v.i = ((unsigned int)u) << 16; return v.f;
}
DEVI unsigned short f2bf(float f) {
    unsigned int u = __builtin_bit_cast(unsigned int, f);
    unsigned int r = u + 0x7fffu + ((u >> 16) & 1u);   // RNE
    return (unsigned short)(r >> 16);
}
// tanh-form GELU via one v_exp (passed at 0.03125 since round 7)
DEVI float gelu_fast(float v) {
    float t = v * v;
    float z = v * (1.5957691216057308f + 0.07135481627f * t);
    float e = __expf(z);
    float r = 2.0f / (1.0f + e);
    return v - 0.5f * v * r;
}

// async global->LDS, 16B per lane; LDS dest is wave-uniform base + lane*16
typedef __attribute__((address_space(3))) unsigned char       lds_u8;
typedef __attribute__((address_space(1))) const unsigned char g_u8;
DEVI void gl_lds16(const void* g, void* l) {
    __builtin_amdgcn_global_load_lds((g_u8*)g, (lds_u8*)l, 16, 0, 0);
}

// ---------------------------------------------------------------------------
// K0: convert + pad weights fp32 -> bf16, folding LN gammas.
// ---------------------------------------------------------------------------
__global__ __launch_bounds__(256) void k_wconv(const float* __restrict__ wqkv,
                                               const float* __restrict__ wout,
                                               const float* __restrict__ wfc1,
                                               const float* __restrict__ wfc2,
                                               const float* __restrict__ n3g,
                                               const float* __restrict__ n4g,
                                               unsigned short* __restrict__ oq,
                                               unsigned short* __restrict__ oo,
                                               unsigned short* __restrict__ o1,
                                               unsigned short* __restrict__ o2) {
    int i = blockIdx.x * 256 + threadIdx.x;
    if (i < 122880) {                       // [640][192]
        int r = i / 192, c = i - r * 192;
        oq[i] = (r < 576) ? f2bf(wqkv[i] * n3g[c]) : (unsigned short)0;
    } else if (i < 172032) {                // [256][192]
        int j = i - 122880; int r = j / 192;
        oo[j] = (r < 192) ? f2bf(wout[j]) : (unsigned short)0;
    } else if (i < 319488) {                // [768][192]
        int j = i - 172032; int c = j % 192;
        o1[j] = f2bf(wfc1[j] * n4g[c]);
    } else if (i < 516096) {                // [256][768]
        int j = i - 319488; int r = j / 768;
        o2[j] = (r < 192) ? f2bf(wfc2[j]) : (unsigned short)0;
    }
}

// ---------------------------------------------------------------------------
// K0b: effective biases folding LN beta through the weights.
// ---------------------------------------------------------------------------
__global__ __launch_bounds__(256) void k_bias(const float* __restrict__ wqkv,
                                              const float* __restrict__ bqkv,
                                              const float* __restrict__ n3b,
                                              const float* __restrict__ wfc1,
                                              const float* __restrict__ bfc1,
                                              const float* __restrict__ n4b,
                                              float* __restrict__ beffq,
                                              float* __restrict__ beff1) {
    int wid = blockIdx.x * 4 + (threadIdx.x >> 6);
    int lane = threadIdx.x & 63;
    const float* wrow; const float* bb; float base; float* dst;
    if (wid < 576) { wrow = wqkv + (size_t)wid * 192; bb = n3b; base = bqkv[wid]; dst = beffq + wid; }
    else { int h = wid - 576; wrow = wfc1 + (size_t)h * 192; bb = n4b; base = bfc1[h]; dst = beff1 + h; }
    float s = wrow[lane] * bb[lane] + wrow[lane + 64] * bb[lane + 64]
            + wrow[lane + 128] * bb[lane + 128];
#pragma unroll
    for (int off = 32; off; off >>= 1) s += __shfl_xor(s, off);
    if (lane == 0) *dst = base + s;
}

// ---------------------------------------------------------------------------
// K1: fused LN3 + window-partition + qkv GEMM (unchanged from round 10).
// ---------------------------------------------------------------------------
__global__ __launch_bounds__(256) void k_qkv(const float* __restrict__ x,
                                             const unsigned short* __restrict__ Bw,
                                             const float* __restrict__ beff,
                                             unsigned short* __restrict__ qk,
                                             unsigned short* __restrict__ vt) {
    __shared__ unsigned short As[3][128][64];    // 48 KB, per-subtile swizzle j=c^(r&7)
    __shared__ unsigned short Bs[2][128 * 64];   // 32 KB dbuf
    const int tid = threadIdx.x;
    const int nwg = gridDim.x * gridDim.y;
    const int flat = blockIdx.y * gridDim.x + blockIdx.x;
    const int swz = (flat & 7) * (nwg >> 3) + (flat >> 3);
    const int bx = swz % gridDim.x, by = swz / gridDim.x;
    const int row0 = by * 128, col0 = bx * 128;
    const int wv = tid >> 6, lane = tid & 63, lr = lane & 15, lg = lane >> 4;
    const int wr = wv >> 1, wc = wv & 1;
    const int sr = lane >> 3, sc = lane & 7;

    auto stageB = [&](int t, int buf) {
        int k0 = t * 64;
#pragma unroll
        for (int i = 0; i < 4; i++) {
            int gq = wv * 4 + i;
            int r = gq * 8 + sr;
            int j = sc ^ (r & 7);
            gl_lds16(Bw + (size_t)(col0 + r) * 192 + k0 + j * 8, &Bs[buf][gq * 512]);
        }
    };

    stageB(0, 0);
    {
        int ar = tid >> 1, ah = tid & 1;         // 2 threads/row, 12 chunks each
        int n = row0 + ar;
        int bp = n >> 9, l = n & 511;
        int bb = bp / 144, p = bp - bb * 144;
        int hn = p / 12, wn = p - hn * 12;
        int dn = l >> 6, t_ = l & 63;
        size_t tok = ((size_t)((bb * 8 + dn) * 96 + hn * 8 + (t_ >> 3)) * 96 + wn * 8 + (t_ & 7));
        const float* src = x + tok * 192;
        float sum = 0.f, ssq = 0.f;
#pragma unroll
        for (int ci = 0; ci < 12; ci++) {
            int c = ah * 12 + ci;
            f32x4 a = *reinterpret_cast<const f32x4*>(src + c * 8);
            f32x4 b = *reinterpret_cast<const f32x4*>(src + c * 8 + 4);
            u16x4 pa, pb;
#pragma unroll
            for (int e = 0; e < 4; e++) {
                sum += a[e] + b[e]; ssq += a[e] * a[e] + b[e] * b[e];
                pa[e] = f2bf(a[e]); pb[e] = f2bf(b[e]);
            }
            int j = (c & 7) ^ (ar & 7);
            unsigned short* dst = &As[c >> 3][ar][j * 8];
            *reinterpret_cast<u16x4*>(dst) = pa;
            *reinterpret_cast<u16x4*>(dst + 4) = pb;
        }
        sum += __shfl_xor(sum, 1); ssq += __shfl_xor(ssq, 1);
        float mu = sum * (1.f / 192.f);
        float rs = rsqrtf(ssq * (1.f / 192.f) - mu * mu + 1e-5f);
#pragma unroll
        for (int ci = 0; ci < 12; ci++) {
            int c = ah * 12 + ci;
            int j = (c & 7) ^ (ar & 7);
            unsigned short* p8 = &As[c >> 3][ar][j * 8];
            u16x4 v0 = *reinterpret_cast<u16x4*>(p8);
            u16x4 v1 = *reinterpret_cast<u16x4*>(p8 + 4);
#pragma unroll
            for (int e = 0; e < 4; e++) {
                v0[e] = f2bf((bf2f(v0[e]) - mu) * rs);
                v1[e] = f2bf((bf2f(v1[e]) - mu) * rs);
            }
            *reinterpret_cast<u16x4*>(p8) = v0;
            *reinterpret_cast<u16x4*>(p8 + 4) = v1;
        }
    }
    asm volatile("s_waitcnt lgkmcnt(0)" ::: "memory");

    f32x4 acc[4][4] = {};
#pragma unroll
    for (int t = 0; t < 3; ++t) {
        if (t + 1 < 3) {
            stageB(t + 1, (t + 1) & 1);
            asm volatile("s_waitcnt vmcnt(4)" ::: "memory");
        } else {
            asm volatile("s_waitcnt vmcnt(0)" ::: "memory");
        }
        __builtin_amdgcn_sched_barrier(0);
        __builtin_amdgcn_s_barrier();
        __builtin_amdgcn_sched_barrier(0);
#pragma unroll
        for (int kk = 0; kk < 64; kk += 32) {
            bf16x8 af[4], bf[4];
#pragma unroll
            for (int m = 0; m < 4; m++) {
                int r = wr * 64 + m * 16 + lr;
                int j = ((kk >> 3) + lg) ^ (r & 7);
                af[m] = __builtin_bit_cast(bf16x8,
                    *reinterpret_cast<const u32x4*>(&As[t][r][j * 8]));
            }
#pragma unroll
            for (int n = 0; n < 4; n++) {
                int r = wc * 64 + n * 16 + lr;
                int j = ((kk >> 3) + lg) ^ (r & 7);
                bf[n] = __builtin_bit_cast(bf16x8,
                    *reinterpret_cast<const u32x4*>(&Bs[t & 1][r * 64 + j * 8]));
            }
#pragma unroll
            for (int m = 0; m < 4; m++)
#pragma unroll
                for (int n = 0; n < 4; n++)
                    acc[m][n] = __builtin_amdgcn_mfma_f32_16x16x32_bf16(bf[n], af[m], acc[m][n], 0, 0, 0);
        }
        __builtin_amdgcn_sched_barrier(0);
        __builtin_amdgcn_s_barrier();
        __builtin_amdgcn_sched_barrier(0);
    }

#pragma unroll
    for (int m = 0; m < 4; m++) {
        const int arow = row0 + wr * 64 + m * 16 + lr;
#pragma unroll
        for (int n = 0; n < 4; n++) {
            const int colb = col0 + wc * 64 + n * 16 + lg * 4;
            if (colb < 384) {
                f32x4 b4 = *reinterpret_cast<const f32x4*>(beff + colb);
                float sc2 = (colb < 192) ? 0.1020620726159658f : 1.f;  // 1/sqrt(96) on q
                u16x4 pk;
#pragma unroll
                for (int rr = 0; rr < 4; rr++) pk[rr] = f2bf((acc[m][n][rr] + b4[rr]) * sc2);
                *reinterpret_cast<u16x4*>(qk + (size_t)arow * 384 + colb) = pk;
            } else if (colb < 576) {
                int head = (colb >= 480) ? 1 : 0;
                int bp = arow >> 9, tok = arow & 511;
                size_t vb = ((size_t)(bp * 2 + head) * 96 + (colb - 384 - head * 96)) * 512 + tok;
#pragma unroll
                for (int rr = 0; rr < 4; rr++)
                    vt[vb + (size_t)rr * 512] = f2bf(acc[m][n][rr] + beff[colb + rr]);
            }
        }
    }
}

// ---------------------------------------------------------------------------
// K2: out_proj GEMM (unchanged from round 10).
// ---------------------------------------------------------------------------
__global__ __launch_bounds__(256) void k_oproj(const unsigned short* __restrict__ A,
                                               const unsigned short* __restrict__ Bw,
                                               const float* __restrict__ bias,
                                               unsigned short* __restrict__ ybf,
                                               const float* __restrict__ res) {
    __shared__ unsigned short As[2][128 * 64];
    __shared__ unsigned short Bs[2][128 * 64];
    const int tid = threadIdx.x;
    const int nwg = gridDim.x * gridDim.y;
    const int flat = blockIdx.y * gridDim.x + blockIdx.x;
    const int swz = (flat & 7) * (nwg >> 3) + (flat >> 3);
    const int bx = swz % gridDim.x, by = swz / gridDim.x;
    const int row0 = by * 128, col0 = bx * 128;
    const int wv = tid >> 6, lane = tid & 63, lr = lane & 15, lg = lane >> 4;
    const int wr = wv >> 1, wc = wv & 1;
    const int sr = lane >> 3, sc = lane & 7;
    f32x4 acc[4][4] = {};

    auto stage = [&](int t, int buf) {
        int k0 = t * 64;
#pragma unroll
        for (int i = 0; i < 4; i++) {
            int gq = wv * 4 + i;
            int r = gq * 8 + sr;
            int j = sc ^ (r & 7);
            gl_lds16(A + (size_t)(row0 + r) * 192 + k0 + j * 8, &As[buf][gq * 512]);
        }
#pragma unroll
        for (int i = 0; i < 4; i++) {
            int gq = wv * 4 + i;
            int r = gq * 8 + sr;
            int j = sc ^ (r & 7);
            gl_lds16(Bw + (size_t)(col0 + r) * 192 + k0 + j * 8, &Bs[buf][gq * 512]);
        }
    };

    stage(0, 0);
#pragma unroll
    for (int t = 0; t < 3; ++t) {
        if (t + 1 < 3) {
            stage(t + 1, (t + 1) & 1);
            asm volatile("s_waitcnt vmcnt(8)" ::: "memory");
        } else {
            asm volatile("s_waitcnt vmcnt(0)" ::: "memory");
        }
        __builtin_amdgcn_sched_barrier(0);
        __builtin_amdgcn_s_barrier();
        __builtin_amdgcn_sched_barrier(0);
#pragma unroll
        for (int kk = 0; kk < 64; kk += 32) {
            bf16x8 af[4], bf[4];
#pragma unroll
            for (int m = 0; m < 4; m++) {
                int r = wr * 64 + m * 16 + lr;
                int j = ((kk >> 3) + lg) ^ (r & 7);
                af[m] = __builtin_bit_cast(bf16x8,
                    *reinterpret_cast<const u32x4*>(&As[t & 1][r * 64 + j * 8]));
            }
#pragma unroll
            for (int n = 0; n < 4; n++) {
                int r = wc * 64 + n * 16 + lr;
                int j = ((kk >> 3) + lg) ^ (r & 7);
                bf[n] = __builtin_bit_cast(bf16x8,
                    *reinterpret_cast<const u32x4*>(&Bs[t & 1][r * 64 + j * 8]));
            }
#pragma unroll
            for (int m = 0; m < 4; m++)
#pragma unroll
                for (int n = 0; n < 4; n++)
                    acc[m][n] = __builtin_amdgcn_mfma_f32_16x16x32_bf16(bf[n], af[m], acc[m][n], 0, 0, 0);
        }
        __builtin_amdgcn_sched_barrier(0);
        __builtin_amdgcn_s_barrier();
        __builtin_amdgcn_sched_barrier(0);
    }

#pragma unroll
    for (int m = 0; m < 4; m++) {
        const int arow = row0 + wr * 64 + m * 16 + lr;
        int bp = arow >> 9, l = arow & 511;
        int bb = bp / 144, p = bp - bb * 144;
        int hn = p / 12, wn = p - hn * 12;
        int dn = l >> 6, t_ = l & 63;
        size_t tok = ((size_t)((bb * 8 + dn) * 96 + hn * 8 + (t_ >> 3)) * 96 + wn * 8 + (t_ & 7));
#pragma unroll
        for (int n = 0; n < 4; n++) {
            const int colb = col0 + wc * 64 + n * 16 + lg * 4;
            if (colb < 192) {
                size_t idx = tok * 192 + colb;
                f32x4 r4 = *reinterpret_cast<const f32x4*>(res + idx);
                f32x4 b4 = *reinterpret_cast<const f32x4*>(bias + colb);
                u16x4 pk;
#pragma unroll
                for (int rr = 0; rr < 4; rr++) pk[rr] = f2bf(r4[rr] + acc[m][n][rr] + b4[rr]);
                *reinterpret_cast<u16x4*>(ybf + idx) = pk;
            }
        }
    }
}

// ---------------------------------------------------------------------------
// K3: block-causal attention. Only change: __launch_bounds__(512, 4) so the
// register allocator targets 4 waves/EU (VGPR cap 128 >> ~70 needed) instead
// of throttling to 64 VGPRs and risking spills.
// ---------------------------------------------------------------------------
__global__ __launch_bounds__(512, 4) void k_attn(const unsigned short* __restrict__ qk,
                                                 const unsigned short* __restrict__ vt,
                                                 unsigned short* __restrict__ aout) {
    __shared__ unsigned short Ks[64][104];
    __shared__ unsigned short Vs[96][72];
    __shared__ unsigned short Ps[8][16][72];

    int bid = (blockIdx.x & 7) * 288 + (blockIdx.x >> 3);
    int bp = bid >> 3, rest = bid & 7, head = rest >> 2, pr = rest & 3;
    int tid = threadIdx.x, wv = tid >> 6, lane = tid & 63;
    int lr = lane & 15, lg = lane >> 4;
    int wq = wv & 3, wt = wv >> 2;
    int nk = 2 * pr + 2;

    size_t qrow0 = (size_t)bp * 512 + (size_t)(2 * pr + wt) * 64;
    const unsigned short* vbase = vt + (size_t)(bp * 2 + head) * 96 * 512;
    size_t krowb = (size_t)bp * 512;

    bf16x8 qf[3];
    {
        const unsigned short* qp = qk + (qrow0 + wq * 16 + lr) * 384 + head * 96 + lg * 8;
#pragma unroll
        for (int ks = 0; ks < 3; ks++)
            qf[ks] = __builtin_bit_cast(bf16x8, *reinterpret_cast<const u32x4*>(qp + ks * 32));
    }

    f32x4 o[6] = {};
    float m_ = -1e30f, lsum = 0.f;

    u32x4 sreg[3];
    auto issue = [&](int dnk) {
#pragma unroll
        for (int i = 0; i < 3; i++) {
            int c = tid + i * 512;
            if (c < 768) {
                int r = c / 12, cc = c - r * 12;
                sreg[i] = *reinterpret_cast<const u32x4*>(
                    qk + (krowb + dnk * 64 + r) * 384 + 192 + head * 96 + cc * 8);
            } else {
                int c2 = c - 768; int d = c2 >> 3, tb = c2 & 7;
                sreg[i] = *reinterpret_cast<const u32x4*>(
                    vbase + (size_t)d * 512 + dnk * 64 + tb * 8);
            }
        }
    };
    auto commit = [&]() {
#pragma unroll
        for (int i = 0; i < 3; i++) {
            int c = tid + i * 512;
            if (c < 768) {
                int r = c / 12, cc = c - r * 12;
                *reinterpret_cast<u32x4*>(&Ks[r][cc * 8]) = sreg[i];
            } else {
                int c2 = c - 768; int d = c2 >> 3, tb = c2 & 7;
                *reinterpret_cast<u32x4*>(&Vs[d][tb * 8]) = sreg[i];
            }
        }
    };

    issue(0);
    for (int dnk = 0; dnk < nk; ++dnk) {
        commit();
        __syncthreads();
        if (dnk + 1 < nk) issue(dnk + 1);
        if (wt == 1 || dnk < nk - 1) {
            f32x4 st[4] = {};
#pragma unroll
            for (int ks = 0; ks < 3; ks++) {
#pragma unroll
                for (int ct = 0; ct < 4; ct++) {
                    bf16x8 kf = __builtin_bit_cast(bf16x8,
                        *reinterpret_cast<const u32x4*>(&Ks[ct * 16 + lr][ks * 32 + lg * 8]));
                    st[ct] = __builtin_amdgcn_mfma_f32_16x16x32_bf16(kf, qf[ks], st[ct], 0, 0, 0);
                }
            }
            float mx = st[0][0];
#pragma unroll
            for (int ct = 0; ct < 4; ct++)
#pragma unroll
                for (int rr = 0; rr < 4; rr++) mx = fmaxf(mx, st[ct][rr]);
            mx = fmaxf(mx, __shfl_xor(mx, 16));
            mx = fmaxf(mx, __shfl_xor(mx, 32));
            float mnew = fmaxf(m_, mx);
            float corr = __expf(m_ - mnew);
            m_ = mnew;
            float ps = 0.f;
#pragma unroll
            for (int ct = 0; ct < 4; ct++) {
                u16x4 pk;
#pragma unroll
                for (int rr = 0; rr < 4; rr++) {
                    float pv = __expf(st[ct][rr] - mnew);
                    ps += pv;
                    pk[rr] = f2bf(pv);
                }
                *reinterpret_cast<u16x4*>(&Ps[wv][lr][ct * 16 + lg * 4]) = pk;
            }
            ps += __shfl_xor(ps, 16);
            ps += __shfl_xor(ps, 32);
            lsum = lsum * corr + ps;
#pragma unroll
            for (int rr = 0; rr < 4; rr++) {
                float cr = __shfl(corr, (lane & 48) | (lg * 4 + rr));
#pragma unroll
                for (int nf = 0; nf < 6; nf++) o[nf][rr] *= cr;
            }
#pragma unroll
            for (int kk = 0; kk < 2; kk++) {
                bf16x8 pf = __builtin_bit_cast(bf16x8,
                    *reinterpret_cast<const u32x4*>(&Ps[wv][lr][kk * 32 + lg * 8]));
#pragma unroll
                for (int nf = 0; nf < 6; nf++) {
                    bf16x8 vf = __builtin_bit_cast(bf16x8,
                        *reinterpret_cast<const u32x4*>(&Vs[nf * 16 + lr][kk * 32 + lg * 8]));
                    o[nf] = __builtin_amdgcn_mfma_f32_16x16x32_bf16(pf, vf, o[nf], 0, 0, 0);
                }
            }
        }
        __syncthreads();
    }

#pragma unroll
    for (int rr = 0; rr < 4; rr++) {
        float li = __shfl(lsum, (lane & 48) | (lg * 4 + rr));
        float inv = 1.f / li;
        size_t row = qrow0 + wq * 16 + lg * 4 + rr;
#pragma unroll
        for (int nf = 0; nf < 6; nf++)
            aout[row * 192 + head * 96 + nf * 16 + lr] = f2bf(o[nf][rr] * inv);
    }
}

// ---------------------------------------------------------------------------
// K4: fused MLP v3 (round-10 algorithm). THE FIX: __launch_bounds__(512, 4)
// — 4 waves/EU => VGPR cap 128 (kernel needs ~110: w2r 48 + accO 24 + acc1 8
// + temps). Round 10's plain (512) let the allocator throttle to 64 VGPRs and
// spill the W2 register tile to scratch (VGPR_Count=64, dur 306->435).
// ---------------------------------------------------------------------------
__global__ __launch_bounds__(512, 4) void k_mlp2(const unsigned short* __restrict__ ybf,
                                                 const unsigned short* __restrict__ w1,
                                                 const unsigned short* __restrict__ w2,
                                                 const float* __restrict__ beff1,
                                                 const float* __restrict__ b2,
                                                 float* __restrict__ out) {
    __shared__ unsigned short XN[3][64][64];     // 24 KB
    __shared__ unsigned short Ws1[2][3][64][64]; // 48 KB
    __shared__ unsigned short Hs[64][64];        //  8 KB
    const int tid = threadIdx.x;
    const int bid = (blockIdx.x & 7) * 288 + (blockIdx.x >> 3);   // XCD swizzle
    const int row0 = bid * 64;
    const int wv = tid >> 6, lane = tid & 63, lr = lane & 15, lg = lane >> 4;
    const int wT = wv & 3, oH = wv >> 2;

    // ---- prologue: stage ybf tile -> XN (24 groups, 3/wave) ----
#pragma unroll
    for (int i = 0; i < 3; i++) {
        int g = wv * 3 + i;
        int sub = g >> 3, rg = g & 7;
        int r = rg * 8 + (lane >> 3);
        int c = (lane & 7) ^ (r & 7);
        gl_lds16(ybf + (size_t)(row0 + r) * 192 + sub * 64 + c * 8, &XN[sub][rg * 8][0]);
    }
    auto stageW1 = [&](int s, int buf) {
#pragma unroll
        for (int i = 0; i < 3; i++) {
            int g = wv * 3 + i;
            int sub = g >> 3, rg = g & 7;
            int r = rg * 8 + (lane >> 3);
            int c = (lane & 7) ^ (r & 7);
            gl_lds16(w1 + (size_t)(s * 64 + r) * 192 + sub * 64 + c * 8, &Ws1[buf][sub][rg * 8][0]);
        }
    };
    stageW1(0, 0);
    asm volatile("s_waitcnt vmcnt(3)" ::: "memory");   // XN landed (W1(0) in flight)
    __builtin_amdgcn_sched_barrier(0);
    __builtin_amdgcn_s_barrier();
    __builtin_amdgcn_sched_barrier(0);

    // ---- LN4 in place on XN: 8 threads/row, 3 chunks each ----
    {
        int r = tid >> 3, q = tid & 7;
        float sum = 0.f, ssq = 0.f;
        u16x4 vv[3][2];
#pragma unroll
        for (int ci = 0; ci < 3; ci++) {
            int c = q * 3 + ci;                   // 0..23
            int j = (c & 7) ^ (r & 7);
            unsigned short* p8 = &XN[c >> 3][r][j * 8];
            vv[ci][0] = *reinterpret_cast<u16x4*>(p8);
            vv[ci][1] = *reinterpret_cast<u16x4*>(p8 + 4);
#pragma unroll
            for (int e = 0; e < 4; e++) {
                float a = bf2f(vv[ci][0][e]), b = bf2f(vv[ci][1][e]);
                sum += a + b; ssq += a * a + b * b;
            }
        }
        sum += __shfl_xor(sum, 1); ssq += __shfl_xor(ssq, 1);
        sum += __shfl_xor(sum, 2); ssq += __shfl_xor(ssq, 2);
        sum += __shfl_xor(sum, 4); ssq += __shfl_xor(ssq, 4);
        float mu = sum * (1.f / 192.f);
        float rs = rsqrtf(ssq * (1.f / 192.f) - mu * mu + 1e-5f);
#pragma unroll
        for (int ci = 0; ci < 3; ci++) {
            int c = q * 3 + ci;
            int j = (c & 7) ^ (r & 7);
            unsigned short* p8 = &XN[c >> 3][r][j * 8];
            u16x4 o0, o1;
#pragma unroll
            for (int e = 0; e < 4; e++) {
                o0[e] = f2bf((bf2f(vv[ci][0][e]) - mu) * rs);
                o1[e] = f2bf((bf2f(vv[ci][1][e]) - mu) * rs);
            }
            *reinterpret_cast<u16x4*>(p8) = o0;
            *reinterpret_cast<u16x4*>(p8 + 4) = o1;
        }
    }
    asm volatile("s_waitcnt lgkmcnt(0)" ::: "memory");
    __builtin_amdgcn_sched_barrier(0);
    __builtin_amdgcn_s_barrier();
    __builtin_amdgcn_sched_barrier(0);

    // ---- 12-slab fc1/fc2 interleave ----
    const f32x4 zf = {0.f, 0.f, 0.f, 0.f};
    f32x4 accO[6] = {};
    const int t = wT * 16 + lr;                   // this lane's token row
    for (int s = 0; s < 12; ++s) {
        const int buf = s & 1;
        // W2(s) -> registers (L2-resident; 12 loads/thread)
        u32x4 w2r[6][2];
#pragma unroll
        for (int n = 0; n < 6; n++)
#pragma unroll
            for (int kk = 0; kk < 2; kk++) {
                int o = oH * 96 + n * 16 + lr;
                w2r[n][kk] = *reinterpret_cast<const u32x4*>(
                    w2 + (size_t)o * 768 + s * 64 + kk * 32 + lg * 8);
            }
        __builtin_amdgcn_sched_barrier(0);
        asm volatile("s_waitcnt vmcnt(12)" ::: "memory");   // W1(s) landed; W2(s) flies
        __builtin_amdgcn_sched_barrier(0);
        __builtin_amdgcn_s_barrier();                       // A: Ws1[buf] ready; Hs free
        __builtin_amdgcn_sched_barrier(0);
        if (s + 1 < 12) stageW1(s + 1, buf ^ 1);            // overwrite-safe after A

        // fc1: Hs[token][h] partial; wave covers tokens wT*16.., h half oH*32..
        f32x4 acc1[2];
        acc1[0] = zf; acc1[1] = zf;
#pragma unroll
        for (int kk = 0; kk < 6; kk++) {
            int sub = kk >> 1;
            int j = ((kk & 1) * 4 + lg) ^ (t & 7);
            bf16x8 ax = __builtin_bit_cast(bf16x8,
                *reinterpret_cast<const u32x4*>(&XN[sub][t][j * 8]));
#pragma unroll
            for (int n = 0; n < 2; n++) {
                int hr = oH * 32 + n * 16 + lr;
                int jb = ((kk & 1) * 4 + lg) ^ (hr & 7);
                bf16x8 bw = __builtin_bit_cast(bf16x8,
                    *reinterpret_cast<const u32x4*>(&Ws1[buf][sub][hr][jb * 8]));
                acc1[n] = __builtin_amdgcn_mfma_f32_16x16x32_bf16(bw, ax, acc1[n], 0, 0, 0);
            }
        }
        // gelu + Hs store (chunk-XOR swizzled u16x4)
#pragma unroll
        for (int n = 0; n < 2; n++) {
            int h0 = oH * 32 + n * 16 + lg * 4;              // 0..63 in slab
            f32x4 b4 = *reinterpret_cast<const f32x4*>(beff1 + s * 64 + h0);
            u16x4 pk;
#pragma unroll
            for (int rr = 0; rr < 4; rr++) pk[rr] = f2bf(gelu_fast(acc1[n][rr] + b4[rr]));
            int jw = (h0 >> 3) ^ (t & 7);
            *reinterpret_cast<u16x4*>(&Hs[t][jw * 8 + (h0 & 7)]) = pk;
        }
        if (s < 11) asm volatile("s_waitcnt vmcnt(3) lgkmcnt(0)" ::: "memory");  // W2(s) done
        else        asm volatile("s_waitcnt vmcnt(0) lgkmcnt(0)" ::: "memory");
        __builtin_amdgcn_sched_barrier(0);
        __builtin_amdgcn_s_barrier();                       // B: Hs visible
        __builtin_amdgcn_sched_barrier(0);

        // fc2 partial: accO += H @ W2slab^T (wave covers out cols oH*96..)
#pragma unroll
        for (int kk = 0; kk < 2; kk++) {
            int j = (kk * 4 + lg) ^ (t & 7);
            bf16x8 ah = __builtin_bit_cast(bf16x8,
                *reinterpret_cast<const u32x4*>(&Hs[t][j * 8]));
#pragma unroll
            for (int n = 0; n < 6; n++)
                accO[n] = __builtin_amdgcn_mfma_f32_16x16x32_bf16(
                    __builtin_bit_cast(bf16x8, w2r[n][kk]), ah, accO[n], 0, 0, 0);
        }
    }

    // ---- epilogue: bias + ybf residual -> fp32 out (packed f32x4) ----
    {
        int tr = row0 + t;
#pragma unroll
        for (int n = 0; n < 6; n++) {
            int o0 = oH * 96 + n * 16 + lg * 4;
            f32x4 b4 = *reinterpret_cast<const f32x4*>(b2 + o0);
            u16x4 rb = *reinterpret_cast<const u16x4*>(ybf + (size_t)tr * 192 + o0);
            f32x4 o4;
#pragma unroll
            for (int rr = 0; rr < 4; rr++) o4[rr] = bf2f(rb[rr]) + accO[n][rr] + b4[rr];
            *reinterpret_cast<f32x4*>(out + (size_t)tr * 192 + o0) = o4;
        }
    }
}

// ---------------------------------------------------------------------------
// Launcher. ws arena (~284.2 MB):
//   [0, 113.2M)        qk bf16 [147456][384]
//   [113.2M, 169.9M)   vt bf16 [576][96][512]
//   [169.9M, 226.5M)   attn bf16
//   [226.5M, 283.1M)   ybf bf16
//   [283.1M, 284.2M)   bf16 weights (gamma-folded) + beffq/beff1 fp32
// d_out written only by k_mlp2 (fully rewritten each call => replay safe).
// ---------------------------------------------------------------------------
extern "C" void kernel_launch(void* const* d_in, const int* in_sizes, int n_in,
                              void* d_out, int out_size, void* d_ws, size_t ws_size,
                              hipStream_t stream) {
    const float* x    = (const float*)d_in[0];
    const float* n3g  = (const float*)d_in[1];
    const float* n3b  = (const float*)d_in[2];
    const float* wqkv = (const float*)d_in[3];
    const float* bqkv = (const float*)d_in[4];
    const float* wout = (const float*)d_in[5];
    const float* bout = (const float*)d_in[6];
    const float* n4g  = (const float*)d_in[7];
    const float* n4b  = (const float*)d_in[8];
    const float* wfc1 = (const float*)d_in[9];
    const float* bfc1 = (const float*)d_in[10];
    const float* wfc2 = (const float*)d_in[11];
    const float* bfc2 = (const float*)d_in[12];
    float* out = (float*)d_out;

    char* ws = (char*)d_ws;
    unsigned short* qk    = (unsigned short*)(ws + 0);
    unsigned short* vt    = (unsigned short*)(ws + 113246208);
    unsigned short* attn  = (unsigned short*)(ws + 169869312);
    unsigned short* ybf   = (unsigned short*)(ws + 226492416);
    unsigned short* wq_bf = (unsigned short*)(ws + 283115520);
    unsigned short* wo_bf = (unsigned short*)(ws + 283361280);
    unsigned short* w1_bf = (unsigned short*)(ws + 283459584);
    unsigned short* w2_bf = (unsigned short*)(ws + 283754496);
    float*          beffq = (float*)(ws + 284147712);
    float*          beff1 = (float*)(ws + 284150016);

    k_wconv<<<2016, 256, 0, stream>>>(wqkv, wout, wfc1, wfc2, n3g, n4g, wq_bf, wo_bf, w1_bf, w2_bf);
    k_bias<<<336, 256, 0, stream>>>(wqkv, bqkv, n3b, wfc1, bfc1, n4b, beffq, beff1);
    k_qkv<<<dim3(5, 1152), 256, 0, stream>>>(x, wq_bf, beffq, qk, vt);
    k_attn<<<2304, 512, 0, stream>>>(qk, vt, attn);
    k_oproj<<<dim3(2, 1152), 256, 0, stream>>>(attn, wo_bf, bout, ybf, x);
    k_mlp2<<<2304, 512, 0, stream>>>(ybf, w1_bf, w2_bf, beff1, bfc2, out);
}

// Round 12
// 671.859 us; speedup vs baseline: 1.1438x; 1.1438x over previous
//
#include <hip/hip_runtime.h>
#include <cstdint>
#include <cstddef>

// ---------------------------------------------------------------------------
// Shapes: x (2,8,96,96,192) fp32 ; windows 1x8x8 ; NH=2 ; hd=96 ; L=512 ; MLP 768
// tokens N = 147456 ; Bp = 288 ; Dn = 8
// ---------------------------------------------------------------------------

typedef float   f32x4  __attribute__((ext_vector_type(4)));
typedef __bf16  bf16x8 __attribute__((ext_vector_type(8)));
typedef unsigned int   u32x4  __attribute__((ext_vector_type(4)));
typedef unsigned short u16x4  __attribute__((ext_vector_type(4)));

#define DEVI __device__ __forceinline__

DEVI float bf2f(unsigned short u) {
    union { unsigned int i; float f; } v; v.i = ((unsigned int)u) << 16; return v.f;
}
DEVI unsigned short f2bf(float f) {
    unsigned int u = __builtin_bit_cast(unsigned int, f);
    unsigned int r = u + 0x7fffu + ((u >> 16) & 1u);   // RNE
    return (unsigned short)(r >> 16);
}
// tanh-form GELU via one v_exp (passed at 0.03125 since round 7)
DEVI float gelu_fast(float v) {
    float t = v * v;
    float z = v * (1.5957691216057308f + 0.07135481627f * t);
    float e = __expf(z);
    float r = 2.0f / (1.0f + e);
    return v - 0.5f * v * r;
}

// async global->LDS, 16B per lane; LDS dest is wave-uniform base + lane*16
typedef __attribute__((address_space(3))) unsigned char       lds_u8;
typedef __attribute__((address_space(1))) const unsigned char g_u8;
DEVI void gl_lds16(const void* g, void* l) {
    __builtin_amdgcn_global_load_lds((g_u8*)g, (lds_u8*)l, 16, 0, 0);
}

// ---------------------------------------------------------------------------
// K0: convert + pad weights fp32 -> bf16, folding LN gammas.
// ---------------------------------------------------------------------------
__global__ __launch_bounds__(256) void k_wconv(const float* __restrict__ wqkv,
                                               const float* __restrict__ wout,
                                               const float* __restrict__ wfc1,
                                               const float* __restrict__ wfc2,
                                               const float* __restrict__ n3g,
                                               const float* __restrict__ n4g,
                                               unsigned short* __restrict__ oq,
                                               unsigned short* __restrict__ oo,
                                               unsigned short* __restrict__ o1,
                                               unsigned short* __restrict__ o2) {
    int i = blockIdx.x * 256 + threadIdx.x;
    if (i < 122880) {                       // [640][192]
        int r = i / 192, c = i - r * 192;
        oq[i] = (r < 576) ? f2bf(wqkv[i] * n3g[c]) : (unsigned short)0;
    } else if (i < 172032) {                // [256][192]
        int j = i - 122880; int r = j / 192;
        oo[j] = (r < 192) ? f2bf(wout[j]) : (unsigned short)0;
    } else if (i < 319488) {                // [768][192]
        int j = i - 172032; int c = j % 192;
        o1[j] = f2bf(wfc1[j] * n4g[c]);
    } else if (i < 516096) {                // [256][768]
        int j = i - 319488; int r = j / 768;
        o2[j] = (r < 192) ? f2bf(wfc2[j]) : (unsigned short)0;
    }
}

// ---------------------------------------------------------------------------
// K0b: effective biases folding LN beta through the (raw) weights.
// ---------------------------------------------------------------------------
__global__ __launch_bounds__(256) void k_bias(const float* __restrict__ wqkv,
                                              const float* __restrict__ bqkv,
                                              const float* __restrict__ n3b,
                                              const float* __restrict__ wfc1,
                                              const float* __restrict__ bfc1,
                                              const float* __restrict__ n4b,
                                              float* __restrict__ beffq,
                                              float* __restrict__ beff1) {
    int wid = blockIdx.x * 4 + (threadIdx.x >> 6);
    int lane = threadIdx.x & 63;
    const float* wrow; const float* bb; float base; float* dst;
    if (wid < 576) { wrow = wqkv + (size_t)wid * 192; bb = n3b; base = bqkv[wid]; dst = beffq + wid; }
    else { int h = wid - 576; wrow = wfc1 + (size_t)h * 192; bb = n4b; base = bfc1[h]; dst = beff1 + h; }
    float s = wrow[lane] * bb[lane] + wrow[lane + 64] * bb[lane + 64]
            + wrow[lane + 128] * bb[lane + 128];
#pragma unroll
    for (int off = 32; off; off >>= 1) s += __shfl_xor(s, off);
    if (lane == 0) *dst = base + s;
}

// ---------------------------------------------------------------------------
// K1: LayerNorm(norm3) WITHOUT affine (folded into weights) + window
// partition -> h bf16 [288][512][192]. One wave per token.
// ---------------------------------------------------------------------------
__global__ __launch_bounds__(256) void k_ln3(const float* __restrict__ x,
                                             unsigned short* __restrict__ h) {
    int w = threadIdx.x >> 6, lane = threadIdx.x & 63;
    int token = blockIdx.x * 4 + w;
    const float* xp = x + (size_t)token * 192;
    float v0 = xp[lane], v1 = xp[lane + 64], v2 = xp[lane + 128];
    float s = v0 + v1 + v2;
#pragma unroll
    for (int off = 32; off; off >>= 1) s += __shfl_xor(s, off);
    float mean = s * (1.f / 192.f);
    float d0 = v0 - mean, d1 = v1 - mean, d2 = v2 - mean;
    float q = d0 * d0 + d1 * d1 + d2 * d2;
#pragma unroll
    for (int off = 32; off; off >>= 1) q += __shfl_xor(q, off);
    float rs = rsqrtf(q * (1.f / 192.f) + 1e-5f);
    int b  = token / (8 * 96 * 96);
    int r0 = token - b * (8 * 96 * 96);
    int d  = r0 / (96 * 96);
    int r1 = r0 - d * (96 * 96);
    int hh = r1 / 96;
    int ww = r1 - hh * 96;
    int bp = b * 144 + (hh >> 3) * 12 + (ww >> 3);
    int l  = d * 64 + (hh & 7) * 8 + (ww & 7);
    unsigned short* hp = h + ((size_t)bp * 512 + l) * 192;
    hp[lane]       = f2bf(d0 * rs);
    hp[lane + 64]  = f2bf(d1 * rs);
    hp[lane + 128] = f2bf(d2 * rs);
}

// ---------------------------------------------------------------------------
// K2: 128xBN GEMM (BN = NF*32), 64KB-class dbuf + counted-vmcnt pipeline
// (R6/R7 proven structure), swapped-operand packed epilogues.
// EPI 0 (NF=4, grid 5x1152): qkv -> qk (q scaled) + vt (v transposed)
// EPI 1 (NF=3, grid 2x1152): out_proj + window-reverse + x residual -> ybf
// ---------------------------------------------------------------------------
template <int EPI, int K, int NF>
__global__ __launch_bounds__(256) void k_gemm128(const unsigned short* __restrict__ A,
                                                 const unsigned short* __restrict__ Bw,
                                                 const float* __restrict__ bias,
                                                 unsigned short* __restrict__ outb,
                                                 unsigned short* __restrict__ vt,
                                                 const float* __restrict__ res) {
    __shared__ unsigned short As[2][128 * 64];
    __shared__ unsigned short Bs[2][NF * 32 * 64];
    const int tid = threadIdx.x;
    const int nwg = gridDim.x * gridDim.y;
    const int flat = blockIdx.y * gridDim.x + blockIdx.x;
    const int swz = (flat & 7) * (nwg >> 3) + (flat >> 3);
    const int bx = swz % gridDim.x, by = swz / gridDim.x;
    const int row0 = by * 128, col0 = bx * (NF * 32);
    const int wv = tid >> 6, lane = tid & 63, lr = lane & 15, lg = lane >> 4;
    const int wr = wv >> 1, wc = wv & 1;
    const int sr = lane >> 3, sc = lane & 7;
    f32x4 acc[4][NF] = {};

    auto stage = [&](int t, int buf) {
        int k0 = t * 64;
#pragma unroll
        for (int i = 0; i < 4; i++) {
            int gq = wv * 4 + i;
            int r = gq * 8 + sr;
            int j = sc ^ (r & 7);
            gl_lds16(A + (size_t)(row0 + r) * K + k0 + j * 8, &As[buf][gq * 512]);
        }
#pragma unroll
        for (int i = 0; i < NF; i++) {
            int gq = wv * NF + i;
            int r = gq * 8 + sr;
            int j = sc ^ (r & 7);
            gl_lds16(Bw + (size_t)(col0 + r) * K + k0 + j * 8, &Bs[buf][gq * 512]);
        }
    };

    const int NT = K / 64;
    stage(0, 0);
    for (int t = 0; t < NT; ++t) {
        int cur = t & 1;
        if (t + 1 < NT) {
            stage(t + 1, cur ^ 1);
            if constexpr (NF == 4) asm volatile("s_waitcnt vmcnt(8)" ::: "memory");
            else                   asm volatile("s_waitcnt vmcnt(7)" ::: "memory");
        } else {
            asm volatile("s_waitcnt vmcnt(0)" ::: "memory");
        }
        __builtin_amdgcn_sched_barrier(0);
        __builtin_amdgcn_s_barrier();
        __builtin_amdgcn_sched_barrier(0);
#pragma unroll
        for (int kk = 0; kk < 64; kk += 32) {
            bf16x8 af[4], bf[NF];
#pragma unroll
            for (int m = 0; m < 4; m++) {
                int r = wr * 64 + m * 16 + lr;
                int j = ((kk >> 3) + lg) ^ (r & 7);
                af[m] = __builtin_bit_cast(bf16x8,
                    *reinterpret_cast<const u32x4*>(&As[cur][r * 64 + j * 8]));
            }
#pragma unroll
            for (int n = 0; n < NF; n++) {
                int r = wc * (NF * 16) + n * 16 + lr;
                int j = ((kk >> 3) + lg) ^ (r & 7);
                bf[n] = __builtin_bit_cast(bf16x8,
                    *reinterpret_cast<const u32x4*>(&Bs[cur][r * 64 + j * 8]));
            }
#pragma unroll
            for (int m = 0; m < 4; m++)
#pragma unroll
                for (int n = 0; n < NF; n++)
                    acc[m][n] = __builtin_amdgcn_mfma_f32_16x16x32_bf16(bf[n], af[m], acc[m][n], 0, 0, 0);
        }
        __builtin_amdgcn_sched_barrier(0);
        __builtin_amdgcn_s_barrier();
        __builtin_amdgcn_sched_barrier(0);
    }

#pragma unroll
    for (int m = 0; m < 4; m++) {
        const int arow = row0 + wr * 64 + m * 16 + lr;
        if constexpr (EPI == 0) {
#pragma unroll
            for (int n = 0; n < NF; n++) {
                const int colb = col0 + wc * (NF * 16) + n * 16 + lg * 4;
                if (colb < 384) {
                    f32x4 b4 = *reinterpret_cast<const f32x4*>(bias + colb);
                    float sc2 = (colb < 192) ? 0.1020620726159658f : 1.f;  // 1/sqrt(96) on q
                    u16x4 pk;
#pragma unroll
                    for (int rr = 0; rr < 4; rr++) pk[rr] = f2bf((acc[m][n][rr] + b4[rr]) * sc2);
                    *reinterpret_cast<u16x4*>(outb + (size_t)arow * 384 + colb) = pk;
                } else if (colb < 576) {
                    int head = (colb >= 480) ? 1 : 0;
                    int bp = arow >> 9, tok = arow & 511;
                    size_t vb = ((size_t)(bp * 2 + head) * 96 + (colb - 384 - head * 96)) * 512 + tok;
#pragma unroll
                    for (int rr = 0; rr < 4; rr++)
                        vt[vb + (size_t)rr * 512] = f2bf(acc[m][n][rr] + bias[colb + rr]);
                }
            }
        } else {
            int bp = arow >> 9, l = arow & 511;
            int bb = bp / 144, p = bp - bb * 144;
            int hn = p / 12, wn = p - hn * 12;
            int dn = l >> 6, t_ = l & 63;
            size_t tok = ((size_t)((bb * 8 + dn) * 96 + hn * 8 + (t_ >> 3)) * 96 + wn * 8 + (t_ & 7));
#pragma unroll
            for (int n = 0; n < NF; n++) {
                const int colb = col0 + wc * (NF * 16) + n * 16 + lg * 4;   // < 192 by construction
                size_t idx = tok * 192 + colb;
                f32x4 r4 = *reinterpret_cast<const f32x4*>(res + idx);
                f32x4 b4 = *reinterpret_cast<const f32x4*>(bias + colb);
                u16x4 pk;
#pragma unroll
                for (int rr = 0; rr < 4; rr++) pk[rr] = f2bf(r4[rr] + acc[m][n][rr] + b4[rr]);
                *reinterpret_cast<u16x4*>(outb + idx) = pk;
            }
        }
    }
}

// ---------------------------------------------------------------------------
// K3: block-causal attention (unchanged, plain 512 bounds as in round 9).
// ---------------------------------------------------------------------------
__global__ __launch_bounds__(512) void k_attn(const unsigned short* __restrict__ qk,
                                              const unsigned short* __restrict__ vt,
                                              unsigned short* __restrict__ aout) {
    __shared__ unsigned short Ks[64][104];
    __shared__ unsigned short Vs[96][72];
    __shared__ unsigned short Ps[8][16][72];

    int bid = (blockIdx.x & 7) * 288 + (blockIdx.x >> 3);
    int bp = bid >> 3, rest = bid & 7, head = rest >> 2, pr = rest & 3;
    int tid = threadIdx.x, wv = tid >> 6, lane = tid & 63;
    int lr = lane & 15, lg = lane >> 4;
    int wq = wv & 3, wt = wv >> 2;
    int nk = 2 * pr + 2;

    size_t qrow0 = (size_t)bp * 512 + (size_t)(2 * pr + wt) * 64;
    const unsigned short* vbase = vt + (size_t)(bp * 2 + head) * 96 * 512;
    size_t krowb = (size_t)bp * 512;

    bf16x8 qf[3];
    {
        const unsigned short* qp = qk + (qrow0 + wq * 16 + lr) * 384 + head * 96 + lg * 8;
#pragma unroll
        for (int ks = 0; ks < 3; ks++)
            qf[ks] = __builtin_bit_cast(bf16x8, *reinterpret_cast<const u32x4*>(qp + ks * 32));
    }

    f32x4 o[6] = {};
    float m_ = -1e30f, lsum = 0.f;

    u32x4 sreg[3];
    auto issue = [&](int dnk) {
#pragma unroll
        for (int i = 0; i < 3; i++) {
            int c = tid + i * 512;
            if (c < 768) {
                int r = c / 12, cc = c - r * 12;
                sreg[i] = *reinterpret_cast<const u32x4*>(
                    qk + (krowb + dnk * 64 + r) * 384 + 192 + head * 96 + cc * 8);
            } else {
                int c2 = c - 768; int d = c2 >> 3, tb = c2 & 7;
                sreg[i] = *reinterpret_cast<const u32x4*>(
                    vbase + (size_t)d * 512 + dnk * 64 + tb * 8);
            }
        }
    };
    auto commit = [&]() {
#pragma unroll
        for (int i = 0; i < 3; i++) {
            int c = tid + i * 512;
            if (c < 768) {
                int r = c / 12, cc = c - r * 12;
                *reinterpret_cast<u32x4*>(&Ks[r][cc * 8]) = sreg[i];
            } else {
                int c2 = c - 768; int d = c2 >> 3, tb = c2 & 7;
                *reinterpret_cast<u32x4*>(&Vs[d][tb * 8]) = sreg[i];
            }
        }
    };

    issue(0);
    for (int dnk = 0; dnk < nk; ++dnk) {
        commit();
        __syncthreads();
        if (dnk + 1 < nk) issue(dnk + 1);
        if (wt == 1 || dnk < nk - 1) {
            f32x4 st[4] = {};
#pragma unroll
            for (int ks = 0; ks < 3; ks++) {
#pragma unroll
                for (int ct = 0; ct < 4; ct++) {
                    bf16x8 kf = __builtin_bit_cast(bf16x8,
                        *reinterpret_cast<const u32x4*>(&Ks[ct * 16 + lr][ks * 32 + lg * 8]));
                    st[ct] = __builtin_amdgcn_mfma_f32_16x16x32_bf16(kf, qf[ks], st[ct], 0, 0, 0);
                }
            }
            float mx = st[0][0];
#pragma unroll
            for (int ct = 0; ct < 4; ct++)
#pragma unroll
                for (int rr = 0; rr < 4; rr++) mx = fmaxf(mx, st[ct][rr]);
            mx = fmaxf(mx, __shfl_xor(mx, 16));
            mx = fmaxf(mx, __shfl_xor(mx, 32));
            float mnew = fmaxf(m_, mx);
            float corr = __expf(m_ - mnew);
            m_ = mnew;
            float ps = 0.f;
#pragma unroll
            for (int ct = 0; ct < 4; ct++) {
                u16x4 pk;
#pragma unroll
                for (int rr = 0; rr < 4; rr++) {
                    float pv = __expf(st[ct][rr] - mnew);
                    ps += pv;
                    pk[rr] = f2bf(pv);
                }
                *reinterpret_cast<u16x4*>(&Ps[wv][lr][ct * 16 + lg * 4]) = pk;
            }
            ps += __shfl_xor(ps, 16);
            ps += __shfl_xor(ps, 32);
            lsum = lsum * corr + ps;
#pragma unroll
            for (int rr = 0; rr < 4; rr++) {
                float cr = __shfl(corr, (lane & 48) | (lg * 4 + rr));
#pragma unroll
                for (int nf = 0; nf < 6; nf++) o[nf][rr] *= cr;
            }
#pragma unroll
            for (int kk = 0; kk < 2; kk++) {
                bf16x8 pf = __builtin_bit_cast(bf16x8,
                    *reinterpret_cast<const u32x4*>(&Ps[wv][lr][kk * 32 + lg * 8]));
#pragma unroll
                for (int nf = 0; nf < 6; nf++) {
                    bf16x8 vf = __builtin_bit_cast(bf16x8,
                        *reinterpret_cast<const u32x4*>(&Vs[nf * 16 + lr][kk * 32 + lg * 8]));
                    o[nf] = __builtin_amdgcn_mfma_f32_16x16x32_bf16(pf, vf, o[nf], 0, 0, 0);
                }
            }
        }
        __syncthreads();
    }

#pragma unroll
    for (int rr = 0; rr < 4; rr++) {
        float li = __shfl(lsum, (lane & 48) | (lg * 4 + rr));
        float inv = 1.f / li;
        size_t row = qrow0 + wq * 16 + lg * 4 + rr;
#pragma unroll
        for (int nf = 0; nf < 6; nf++)
            aout[row * 192 + head * 96 + nf * 16 + lr] = f2bf(o[nf][rr] * inv);
    }
}

// ---------------------------------------------------------------------------
// K4: fused MLP v4 — LN4 + fc1 + GELU + fc2 + residual per 64-token block.
// De-risked vs v2/v3: LDS = 32 KB ONLY (XN 24 + Hs 8; NO weight LDS).
// W1/W2 slabs are loaded straight from L2 into SHORT-LIVED register
// fragments right before their MFMA (<=8 VGPR live per group) — nothing for
// the allocator to spill, no cross-barrier vmcnt games. 256 thr, (256,4):
// 16 waves/CU (4/SIMD), 4 WG/CU.
// Waves: tHalf = wv&1 (32 tokens), oH = wv>>1 (hidden/out half).
// 12 slabs of 64 hidden; per slab: fc1(24 MFMA) -> gelu -> Hs -> barrier ->
// fc2(24 MFMA into accO) -> barrier. Hidden never touches HBM.
// ---------------------------------------------------------------------------
__global__ __launch_bounds__(256, 4) void k_mlp3(const unsigned short* __restrict__ ybf,
                                                 const unsigned short* __restrict__ w1,
                                                 const unsigned short* __restrict__ w2,
                                                 const float* __restrict__ beff1,
                                                 const float* __restrict__ b2,
                                                 float* __restrict__ out) {
    __shared__ unsigned short XN[3][64][64];     // 24 KB, chunk-XOR swizzled
    __shared__ unsigned short Hs[64][64];        //  8 KB, chunk-XOR swizzled
    const int tid = threadIdx.x;
    const int bid = (blockIdx.x & 7) * 288 + (blockIdx.x >> 3);   // XCD swizzle
    const int row0 = bid * 64;
    const int wv = tid >> 6, lane = tid & 63, lr = lane & 15, lg = lane >> 4;
    const int tHalf = wv & 1, oH = wv >> 1;

    // ---- stage ybf tile -> XN (24 1KB-groups, 6 per wave) ----
#pragma unroll
    for (int i = 0; i < 6; i++) {
        int g = wv * 6 + i;
        int sub = g >> 3, rg = g & 7;
        int r = rg * 8 + (lane >> 3);
        int c = (lane & 7) ^ (r & 7);
        gl_lds16(ybf + (size_t)(row0 + r) * 192 + sub * 64 + c * 8, &XN[sub][rg * 8][0]);
    }
    __syncthreads();   // drains vmcnt(0): XN complete

    // ---- LN4 in place on XN (no affine: folded into w1/beff1): 4 thr/row ----
    {
        int r = tid >> 2, q = tid & 3;
        float sum = 0.f, ssq = 0.f;
        u16x4 vv[6][2];
#pragma unroll
        for (int ci = 0; ci < 6; ci++) {
            int c = q * 6 + ci;                   // 0..23
            int j = (c & 7) ^ (r & 7);
            unsigned short* p8 = &XN[c >> 3][r][j * 8];
            vv[ci][0] = *reinterpret_cast<u16x4*>(p8);
            vv[ci][1] = *reinterpret_cast<u16x4*>(p8 + 4);
#pragma unroll
            for (int e = 0; e < 4; e++) {
                float a = bf2f(vv[ci][0][e]), b = bf2f(vv[ci][1][e]);
                sum += a + b; ssq += a * a + b * b;
            }
        }
        sum += __shfl_xor(sum, 1); ssq += __shfl_xor(ssq, 1);
        sum += __shfl_xor(sum, 2); ssq += __shfl_xor(ssq, 2);
        float mu = sum * (1.f / 192.f);
        float rs = rsqrtf(ssq * (1.f / 192.f) - mu * mu + 1e-5f);
#pragma unroll
        for (int ci = 0; ci < 6; ci++) {
            int c = q * 6 + ci;
            int j = (c & 7) ^ (r & 7);
            unsigned short* p8 = &XN[c >> 3][r][j * 8];
            u16x4 o0, o1;
#pragma unroll
            for (int e = 0; e < 4; e++) {
                o0[e] = f2bf((bf2f(vv[ci][0][e]) - mu) * rs);
                o1[e] = f2bf((bf2f(vv[ci][1][e]) - mu) * rs);
            }
            *reinterpret_cast<u16x4*>(p8) = o0;
            *reinterpret_cast<u16x4*>(p8 + 4) = o1;
        }
    }
    __syncthreads();   // LN'd XN visible to all waves

    // ---- 12-slab fc1/fc2 interleave, weights via short-lived reg frags ----
    f32x4 accO[2][6] = {};
    for (int s = 0; s < 12; ++s) {
        // fc1: acc1[m][n] over tokens (tHalf*32 + m*16) x hidden (oH*32 + n*16)
        f32x4 acc1[2][2] = {};
#pragma unroll
        for (int kk = 0; kk < 6; kk++) {
            int sub = kk >> 1;
            bf16x8 ax[2];
#pragma unroll
            for (int m = 0; m < 2; m++) {
                int t = tHalf * 32 + m * 16 + lr;
                int j = ((kk & 1) * 4 + lg) ^ (t & 7);
                ax[m] = __builtin_bit_cast(bf16x8,
                    *reinterpret_cast<const u32x4*>(&XN[sub][t][j * 8]));
            }
#pragma unroll
            for (int n = 0; n < 2; n++) {
                bf16x8 bw = __builtin_bit_cast(bf16x8, *reinterpret_cast<const u32x4*>(
                    w1 + (size_t)(s * 64 + oH * 32 + n * 16 + lr) * 192 + kk * 32 + lg * 8));
#pragma unroll
                for (int m = 0; m < 2; m++)
                    acc1[m][n] = __builtin_amdgcn_mfma_f32_16x16x32_bf16(bw, ax[m], acc1[m][n], 0, 0, 0);
            }
        }
        // gelu + Hs store (chunk-XOR swizzled u16x4)
#pragma unroll
        for (int m = 0; m < 2; m++) {
            int t = tHalf * 32 + m * 16 + lr;
#pragma unroll
            for (int n = 0; n < 2; n++) {
                int h0 = oH * 32 + n * 16 + lg * 4;            // 0..63 in slab
                f32x4 b4 = *reinterpret_cast<const f32x4*>(beff1 + s * 64 + h0);
                u16x4 pk;
#pragma unroll
                for (int rr = 0; rr < 4; rr++) pk[rr] = f2bf(gelu_fast(acc1[m][n][rr] + b4[rr]));
                int jw = (h0 >> 3) ^ (t & 7);
                *reinterpret_cast<u16x4*>(&Hs[t][jw * 8 + (h0 & 7)]) = pk;
            }
        }
        __syncthreads();   // Hs visible (both oH halves)

        // fc2 partial: accO[m][n] over tokens x out cols (oH*96 + n*16)
#pragma unroll
        for (int kk = 0; kk < 2; kk++) {
            bf16x8 ah[2];
#pragma unroll
            for (int m = 0; m < 2; m++) {
                int t = tHalf * 32 + m * 16 + lr;
                int j = (kk * 4 + lg) ^ (t & 7);
                ah[m] = __builtin_bit_cast(bf16x8,
                    *reinterpret_cast<const u32x4*>(&Hs[t][j * 8]));
            }
#pragma unroll
            for (int n = 0; n < 6; n++) {
                bf16x8 bw = __builtin_bit_cast(bf16x8, *reinterpret_cast<const u32x4*>(
                    w2 + (size_t)(oH * 96 + n * 16 + lr) * 768 + s * 64 + kk * 32 + lg * 8));
#pragma unroll
                for (int m = 0; m < 2; m++)
                    accO[m][n] = __builtin_amdgcn_mfma_f32_16x16x32_bf16(bw, ah[m], accO[m][n], 0, 0, 0);
            }
        }
        __syncthreads();   // fc2 reads done before next slab's Hs overwrite
    }

    // ---- epilogue: bias + ybf residual -> fp32 out (packed f32x4) ----
#pragma unroll
    for (int m = 0; m < 2; m++) {
        int t = row0 + tHalf * 32 + m * 16 + lr;
#pragma unroll
        for (int n = 0; n < 6; n++) {
            int o0 = oH * 96 + n * 16 + lg * 4;
            f32x4 b4 = *reinterpret_cast<const f32x4*>(b2 + o0);
            u16x4 rb = *reinterpret_cast<const u16x4*>(ybf + (size_t)t * 192 + o0);
            f32x4 o4;
#pragma unroll
            for (int rr = 0; rr < 4; rr++) o4[rr] = bf2f(rb[rr]) + accO[m][n][rr] + b4[rr];
            *reinterpret_cast<f32x4*>(out + (size_t)t * 192 + o0) = o4;
        }
    }
}

// ---------------------------------------------------------------------------
// Launcher. ws arena (~340.8 MB):
//   [0, 113.2M)        qk bf16 [147456][384]
//   [113.2M, 169.9M)   vt bf16 [576][96][512]
//   [169.9M, 226.5M)   attn bf16
//   [226.5M, 283.1M)   ybf bf16
//   [283.1M, 339.7M)   h bf16 [147456][192] (normalized-only LN3 out)
//   [339.7M, 340.8M)   bf16 weights (gamma-folded) + beffq/beff1 fp32
// d_out written only by k_mlp3 (fully rewritten each call => replay safe).
// ---------------------------------------------------------------------------
extern "C" void kernel_launch(void* const* d_in, const int* in_sizes, int n_in,
                              void* d_out, int out_size, void* d_ws, size_t ws_size,
                              hipStream_t stream) {
    const float* x    = (const float*)d_in[0];
    const float* n3g  = (const float*)d_in[1];
    const float* n3b  = (const float*)d_in[2];
    const float* wqkv = (const float*)d_in[3];
    const float* bqkv = (const float*)d_in[4];
    const float* wout = (const float*)d_in[5];
    const float* bout = (const float*)d_in[6];
    const float* n4g  = (const float*)d_in[7];
    const float* n4b  = (const float*)d_in[8];
    const float* wfc1 = (const float*)d_in[9];
    const float* bfc1 = (const float*)d_in[10];
    const float* wfc2 = (const float*)d_in[11];
    const float* bfc2 = (const float*)d_in[12];
    float* out = (float*)d_out;

    char* ws = (char*)d_ws;
    unsigned short* qk    = (unsigned short*)(ws + 0);
    unsigned short* vt    = (unsigned short*)(ws + 113246208);
    unsigned short* attn  = (unsigned short*)(ws + 169869312);
    unsigned short* ybf   = (unsigned short*)(ws + 226492416);
    unsigned short* h     = (unsigned short*)(ws + 283115520);
    unsigned short* wq_bf = (unsigned short*)(ws + 339738624);
    unsigned short* wo_bf = (unsigned short*)(ws + 339984384);
    unsigned short* w1_bf = (unsigned short*)(ws + 340082688);
    unsigned short* w2_bf = (unsigned short*)(ws + 340377600);
    float*          beffq = (float*)(ws + 340770816);
    float*          beff1 = (float*)(ws + 340773120);

    k_wconv<<<2016, 256, 0, stream>>>(wqkv, wout, wfc1, wfc2, n3g, n4g, wq_bf, wo_bf, w1_bf, w2_bf);
    k_bias<<<336, 256, 0, stream>>>(wqkv, bqkv, n3b, wfc1, bfc1, n4b, beffq, beff1);
    k_ln3<<<36864, 256, 0, stream>>>(x, h);
    k_gemm128<0, 192, 4><<<dim3(5, 1152), 256, 0, stream>>>(h, wq_bf, beffq, qk, vt, nullptr);
    k_attn<<<2304, 512, 0, stream>>>(qk, vt, attn);
    k_gemm128<1, 192, 3><<<dim3(2, 1152), 256, 0, stream>>>(attn, wo_bf, bout, ybf, nullptr, x);
    k_mlp3<<<2304, 256, 0, stream>>>(ybf, w1_bf, w2_bf, beff1, bfc2, out);
}

// Round 13
// 551.362 us; speedup vs baseline: 1.3937x; 1.2185x over previous
//
#include <hip/hip_runtime.h>
#include <cstdint>
#include <cstddef>

// ---------------------------------------------------------------------------
// Shapes: x (2,8,96,96,192) fp32 ; windows 1x8x8 ; NH=2 ; hd=96 ; L=512 ; MLP 768
// tokens N = 147456 ; Bp = 288 ; Dn = 8
// ---------------------------------------------------------------------------

typedef float   f32x4  __attribute__((ext_vector_type(4)));
typedef __bf16  bf16x8 __attribute__((ext_vector_type(8)));
typedef unsigned int   u32x4  __attribute__((ext_vector_type(4)));
typedef unsigned short u16x4  __attribute__((ext_vector_type(4)));

#define DEVI __device__ __forceinline__

DEVI float bf2f(unsigned short u) {
    union { unsigned int i; float f; } v; v.i = ((unsigned int)u) << 16; return v.f;
}
DEVI unsigned short f2bf(float f) {
    unsigned int u = __builtin_bit_cast(unsigned int, f);
    unsigned int r = u + 0x7fffu + ((u >> 16) & 1u);   // RNE
    return (unsigned short)(r >> 16);
}
// tanh-form GELU via one v_exp (passed at 0.03125 since round 7)
DEVI float gelu_fast(float v) {
    float t = v * v;
    float z = v * (1.5957691216057308f + 0.07135481627f * t);
    float e = __expf(z);
    float r = 2.0f / (1.0f + e);
    return v - 0.5f * v * r;
}

// async global->LDS, 16B per lane; LDS dest is wave-uniform base + lane*16
typedef __attribute__((address_space(3))) unsigned char       lds_u8;
typedef __attribute__((address_space(1))) const unsigned char g_u8;
DEVI void gl_lds16(const void* g, void* l) {
    __builtin_amdgcn_global_load_lds((g_u8*)g, (lds_u8*)l, 16, 0, 0);
}

// ---------------------------------------------------------------------------
// K0: convert + pad weights fp32 -> bf16, folding LN gammas.
// ---------------------------------------------------------------------------
__global__ __launch_bounds__(256) void k_wconv(const float* __restrict__ wqkv,
                                               const float* __restrict__ wout,
                                               const float* __restrict__ wfc1,
                                               const float* __restrict__ wfc2,
                                               const float* __restrict__ n3g,
                                               const float* __restrict__ n4g,
                                               unsigned short* __restrict__ oq,
                                               unsigned short* __restrict__ oo,
                                               unsigned short* __restrict__ o1,
                                               unsigned short* __restrict__ o2) {
    int i = blockIdx.x * 256 + threadIdx.x;
    if (i < 122880) {                       // [640][192]
        int r = i / 192, c = i - r * 192;
        oq[i] = (r < 576) ? f2bf(wqkv[i] * n3g[c]) : (unsigned short)0;
    } else if (i < 172032) {                // [256][192]
        int j = i - 122880; int r = j / 192;
        oo[j] = (r < 192) ? f2bf(wout[j]) : (unsigned short)0;
    } else if (i < 319488) {                // [768][192]
        int j = i - 172032; int c = j % 192;
        o1[j] = f2bf(wfc1[j] * n4g[c]);
    } else if (i < 516096) {                // [256][768]
        int j = i - 319488; int r = j / 768;
        o2[j] = (r < 192) ? f2bf(wfc2[j]) : (unsigned short)0;
    }
}

// ---------------------------------------------------------------------------
// K0b: effective biases folding LN beta through the (raw) weights.
// ---------------------------------------------------------------------------
__global__ __launch_bounds__(256) void k_bias(const float* __restrict__ wqkv,
                                              const float* __restrict__ bqkv,
                                              const float* __restrict__ n3b,
                                              const float* __restrict__ wfc1,
                                              const float* __restrict__ bfc1,
                                              const float* __restrict__ n4b,
                                              float* __restrict__ beffq,
                                              float* __restrict__ beff1) {
    int wid = blockIdx.x * 4 + (threadIdx.x >> 6);
    int lane = threadIdx.x & 63;
    const float* wrow; const float* bb; float base; float* dst;
    if (wid < 576) { wrow = wqkv + (size_t)wid * 192; bb = n3b; base = bqkv[wid]; dst = beffq + wid; }
    else { int h = wid - 576; wrow = wfc1 + (size_t)h * 192; bb = n4b; base = bfc1[h]; dst = beff1 + h; }
    float s = wrow[lane] * bb[lane] + wrow[lane + 64] * bb[lane + 64]
            + wrow[lane + 128] * bb[lane + 128];
#pragma unroll
    for (int off = 32; off; off >>= 1) s += __shfl_xor(s, off);
    if (lane == 0) *dst = base + s;
}

// ---------------------------------------------------------------------------
// K1: LayerNorm(norm3) WITHOUT affine (folded into weights) + window
// partition -> h bf16 [288][512][192]. One wave per token.
// ---------------------------------------------------------------------------
__global__ __launch_bounds__(256) void k_ln3(const float* __restrict__ x,
                                             unsigned short* __restrict__ h) {
    int w = threadIdx.x >> 6, lane = threadIdx.x & 63;
    int token = blockIdx.x * 4 + w;
    const float* xp = x + (size_t)token * 192;
    float v0 = xp[lane], v1 = xp[lane + 64], v2 = xp[lane + 128];
    float s = v0 + v1 + v2;
#pragma unroll
    for (int off = 32; off; off >>= 1) s += __shfl_xor(s, off);
    float mean = s * (1.f / 192.f);
    float d0 = v0 - mean, d1 = v1 - mean, d2 = v2 - mean;
    float q = d0 * d0 + d1 * d1 + d2 * d2;
#pragma unroll
    for (int off = 32; off; off >>= 1) q += __shfl_xor(q, off);
    float rs = rsqrtf(q * (1.f / 192.f) + 1e-5f);
    int b  = token / (8 * 96 * 96);
    int r0 = token - b * (8 * 96 * 96);
    int d  = r0 / (96 * 96);
    int r1 = r0 - d * (96 * 96);
    int hh = r1 / 96;
    int ww = r1 - hh * 96;
    int bp = b * 144 + (hh >> 3) * 12 + (ww >> 3);
    int l  = d * 64 + (hh & 7) * 8 + (ww & 7);
    unsigned short* hp = h + ((size_t)bp * 512 + l) * 192;
    hp[lane]       = f2bf(d0 * rs);
    hp[lane + 64]  = f2bf(d1 * rs);
    hp[lane + 128] = f2bf(d2 * rs);
}

// ---------------------------------------------------------------------------
// K5: LayerNorm(norm4) WITHOUT affine on bf16 ybf -> xn4 bf16.
// 8 rows/block, 32 lanes per row, u32-packed loads/stores.
// ---------------------------------------------------------------------------
__global__ __launch_bounds__(256) void k_ln4b(const unsigned short* __restrict__ yb,
                                              unsigned short* __restrict__ xn) {
    int sub = threadIdx.x >> 5, tl = threadIdx.x & 31;
    size_t row = (size_t)blockIdx.x * 8 + sub;
    const unsigned int* rp = reinterpret_cast<const unsigned int*>(yb + row * 192);
    float v[6];
#pragma unroll
    for (int j = 0; j < 3; j++) {
        unsigned int w = rp[tl + 32 * j];
        v[2 * j]     = bf2f((unsigned short)(w & 0xffffu));
        v[2 * j + 1] = bf2f((unsigned short)(w >> 16));
    }
    float s = v[0] + v[1] + v[2] + v[3] + v[4] + v[5];
#pragma unroll
    for (int off = 1; off < 32; off <<= 1) s += __shfl_xor(s, off);
    float mean = s * (1.f / 192.f);
    float q = 0.f;
#pragma unroll
    for (int j = 0; j < 6; j++) { v[j] -= mean; q += v[j] * v[j]; }
#pragma unroll
    for (int off = 1; off < 32; off <<= 1) q += __shfl_xor(q, off);
    float rs = rsqrtf(q * (1.f / 192.f) + 1e-5f);
    unsigned int* op = reinterpret_cast<unsigned int*>(xn + row * 192);
#pragma unroll
    for (int j = 0; j < 3; j++) {
        unsigned short lo = f2bf(v[2 * j]     * rs);
        unsigned short hi = f2bf(v[2 * j + 1] * rs);
        op[tl + 32 * j] = ((unsigned int)hi << 16) | lo;
    }
}

// ---------------------------------------------------------------------------
// K2: 128xBN GEMM (BN = NF*32), dbuf + counted-vmcnt pipeline, swapped-operand
// packed epilogues (lane holds 4 consecutive output cols).
// EPI 0 (NF=4, K=192): qkv -> qk (q scaled) + vt (v transposed)
// EPI 1 (NF=3, K=192): out_proj + window-reverse + x residual -> ybf bf16
// EPI 2 (NF=4, K=192): fc1 + gelu_fast -> hidden bf16 (ld 768)
// EPI 3 (NF=3, K=768): fc2 + ybf residual -> out fp32 (ld 192)
// ---------------------------------------------------------------------------
template <int EPI, int K, int NF>
__global__ __launch_bounds__(256) void k_gemm128(const unsigned short* __restrict__ A,
                                                 const unsigned short* __restrict__ Bw,
                                                 const float* __restrict__ bias,
                                                 unsigned short* __restrict__ outb,
                                                 unsigned short* __restrict__ vt,
                                                 const float* __restrict__ res,
                                                 const unsigned short* __restrict__ resb,
                                                 float* __restrict__ outf) {
    __shared__ unsigned short As[2][128 * 64];
    __shared__ unsigned short Bs[2][NF * 32 * 64];
    const int tid = threadIdx.x;
    const int nwg = gridDim.x * gridDim.y;
    const int flat = blockIdx.y * gridDim.x + blockIdx.x;
    const int swz = (flat & 7) * (nwg >> 3) + (flat >> 3);
    const int bx = swz % gridDim.x, by = swz / gridDim.x;
    const int row0 = by * 128, col0 = bx * (NF * 32);
    const int wv = tid >> 6, lane = tid & 63, lr = lane & 15, lg = lane >> 4;
    const int wr = wv >> 1, wc = wv & 1;
    const int sr = lane >> 3, sc = lane & 7;
    f32x4 acc[4][NF] = {};

    auto stage = [&](int t, int buf) {
        int k0 = t * 64;
#pragma unroll
        for (int i = 0; i < 4; i++) {
            int gq = wv * 4 + i;
            int r = gq * 8 + sr;
            int j = sc ^ (r & 7);
            gl_lds16(A + (size_t)(row0 + r) * K + k0 + j * 8, &As[buf][gq * 512]);
        }
#pragma unroll
        for (int i = 0; i < NF; i++) {
            int gq = wv * NF + i;
            int r = gq * 8 + sr;
            int j = sc ^ (r & 7);
            gl_lds16(Bw + (size_t)(col0 + r) * K + k0 + j * 8, &Bs[buf][gq * 512]);
        }
    };

    const int NT = K / 64;
    stage(0, 0);
    for (int t = 0; t < NT; ++t) {
        int cur = t & 1;
        if (t + 1 < NT) {
            stage(t + 1, cur ^ 1);
            if constexpr (NF == 4) asm volatile("s_waitcnt vmcnt(8)" ::: "memory");
            else                   asm volatile("s_waitcnt vmcnt(7)" ::: "memory");
        } else {
            asm volatile("s_waitcnt vmcnt(0)" ::: "memory");
        }
        __builtin_amdgcn_sched_barrier(0);
        __builtin_amdgcn_s_barrier();
        __builtin_amdgcn_sched_barrier(0);
#pragma unroll
        for (int kk = 0; kk < 64; kk += 32) {
            bf16x8 af[4], bf[NF];
#pragma unroll
            for (int m = 0; m < 4; m++) {
                int r = wr * 64 + m * 16 + lr;
                int j = ((kk >> 3) + lg) ^ (r & 7);
                af[m] = __builtin_bit_cast(bf16x8,
                    *reinterpret_cast<const u32x4*>(&As[cur][r * 64 + j * 8]));
            }
#pragma unroll
            for (int n = 0; n < NF; n++) {
                int r = wc * (NF * 16) + n * 16 + lr;
                int j = ((kk >> 3) + lg) ^ (r & 7);
                bf[n] = __builtin_bit_cast(bf16x8,
                    *reinterpret_cast<const u32x4*>(&Bs[cur][r * 64 + j * 8]));
            }
#pragma unroll
            for (int m = 0; m < 4; m++)
#pragma unroll
                for (int n = 0; n < NF; n++)
                    acc[m][n] = __builtin_amdgcn_mfma_f32_16x16x32_bf16(bf[n], af[m], acc[m][n], 0, 0, 0);
        }
        __builtin_amdgcn_sched_barrier(0);
        __builtin_amdgcn_s_barrier();
        __builtin_amdgcn_sched_barrier(0);
    }

#pragma unroll
    for (int m = 0; m < 4; m++) {
        const int arow = row0 + wr * 64 + m * 16 + lr;
        if constexpr (EPI == 0) {
#pragma unroll
            for (int n = 0; n < NF; n++) {
                const int colb = col0 + wc * (NF * 16) + n * 16 + lg * 4;
                if (colb < 384) {
                    f32x4 b4 = *reinterpret_cast<const f32x4*>(bias + colb);
                    float sc2 = (colb < 192) ? 0.1020620726159658f : 1.f;  // 1/sqrt(96) on q
                    u16x4 pk;
#pragma unroll
                    for (int rr = 0; rr < 4; rr++) pk[rr] = f2bf((acc[m][n][rr] + b4[rr]) * sc2);
                    *reinterpret_cast<u16x4*>(outb + (size_t)arow * 384 + colb) = pk;
                } else if (colb < 576) {
                    int head = (colb >= 480) ? 1 : 0;
                    int bp = arow >> 9, tok = arow & 511;
                    size_t vb = ((size_t)(bp * 2 + head) * 96 + (colb - 384 - head * 96)) * 512 + tok;
#pragma unroll
                    for (int rr = 0; rr < 4; rr++)
                        vt[vb + (size_t)rr * 512] = f2bf(acc[m][n][rr] + bias[colb + rr]);
                }
            }
        } else if constexpr (EPI == 1) {
            int bp = arow >> 9, l = arow & 511;
            int bb = bp / 144, p = bp - bb * 144;
            int hn = p / 12, wn = p - hn * 12;
            int dn = l >> 6, t_ = l & 63;
            size_t tok = ((size_t)((bb * 8 + dn) * 96 + hn * 8 + (t_ >> 3)) * 96 + wn * 8 + (t_ & 7));
#pragma unroll
            for (int n = 0; n < NF; n++) {
                const int colb = col0 + wc * (NF * 16) + n * 16 + lg * 4;   // < 192
                size_t idx = tok * 192 + colb;
                f32x4 r4 = *reinterpret_cast<const f32x4*>(res + idx);
                f32x4 b4 = *reinterpret_cast<const f32x4*>(bias + colb);
                u16x4 pk;
#pragma unroll
                for (int rr = 0; rr < 4; rr++) pk[rr] = f2bf(r4[rr] + acc[m][n][rr] + b4[rr]);
                *reinterpret_cast<u16x4*>(outb + idx) = pk;
            }
        } else if constexpr (EPI == 2) {
#pragma unroll
            for (int n = 0; n < NF; n++) {
                const int colb = col0 + wc * (NF * 16) + n * 16 + lg * 4;   // < 768
                f32x4 b4 = *reinterpret_cast<const f32x4*>(bias + colb);
                u16x4 pk;
#pragma unroll
                for (int rr = 0; rr < 4; rr++) pk[rr] = f2bf(gelu_fast(acc[m][n][rr] + b4[rr]));
                *reinterpret_cast<u16x4*>(outb + (size_t)arow * 768 + colb) = pk;
            }
        } else {
#pragma unroll
            for (int n = 0; n < NF; n++) {
                const int colb = col0 + wc * (NF * 16) + n * 16 + lg * 4;   // < 192
                size_t idx = (size_t)arow * 192 + colb;
                f32x4 b4 = *reinterpret_cast<const f32x4*>(bias + colb);
                u16x4 rb = *reinterpret_cast<const u16x4*>(resb + idx);
                f32x4 o4;
#pragma unroll
                for (int rr = 0; rr < 4; rr++) o4[rr] = bf2f(rb[rr]) + acc[m][n][rr] + b4[rr];
                *reinterpret_cast<f32x4*>(outf + idx) = o4;
            }
        }
    }
}

// ---------------------------------------------------------------------------
// K3: block-causal attention (unchanged).
// ---------------------------------------------------------------------------
__global__ __launch_bounds__(512) void k_attn(const unsigned short* __restrict__ qk,
                                              const unsigned short* __restrict__ vt,
                                              unsigned short* __restrict__ aout) {
    __shared__ unsigned short Ks[64][104];
    __shared__ unsigned short Vs[96][72];
    __shared__ unsigned short Ps[8][16][72];

    int bid = (blockIdx.x & 7) * 288 + (blockIdx.x >> 3);
    int bp = bid >> 3, rest = bid & 7, head = rest >> 2, pr = rest & 3;
    int tid = threadIdx.x, wv = tid >> 6, lane = tid & 63;
    int lr = lane & 15, lg = lane >> 4;
    int wq = wv & 3, wt = wv >> 2;
    int nk = 2 * pr + 2;

    size_t qrow0 = (size_t)bp * 512 + (size_t)(2 * pr + wt) * 64;
    const unsigned short* vbase = vt + (size_t)(bp * 2 + head) * 96 * 512;
    size_t krowb = (size_t)bp * 512;

    bf16x8 qf[3];
    {
        const unsigned short* qp = qk + (qrow0 + wq * 16 + lr) * 384 + head * 96 + lg * 8;
#pragma unroll
        for (int ks = 0; ks < 3; ks++)
            qf[ks] = __builtin_bit_cast(bf16x8, *reinterpret_cast<const u32x4*>(qp + ks * 32));
    }

    f32x4 o[6] = {};
    float m_ = -1e30f, lsum = 0.f;

    u32x4 sreg[3];
    auto issue = [&](int dnk) {
#pragma unroll
        for (int i = 0; i < 3; i++) {
            int c = tid + i * 512;
            if (c < 768) {
                int r = c / 12, cc = c - r * 12;
                sreg[i] = *reinterpret_cast<const u32x4*>(
                    qk + (krowb + dnk * 64 + r) * 384 + 192 + head * 96 + cc * 8);
            } else {
                int c2 = c - 768; int d = c2 >> 3, tb = c2 & 7;
                sreg[i] = *reinterpret_cast<const u32x4*>(
                    vbase + (size_t)d * 512 + dnk * 64 + tb * 8);
            }
        }
    };
    auto commit = [&]() {
#pragma unroll
        for (int i = 0; i < 3; i++) {
            int c = tid + i * 512;
            if (c < 768) {
                int r = c / 12, cc = c - r * 12;
                *reinterpret_cast<u32x4*>(&Ks[r][cc * 8]) = sreg[i];
            } else {
                int c2 = c - 768; int d = c2 >> 3, tb = c2 & 7;
                *reinterpret_cast<u32x4*>(&Vs[d][tb * 8]) = sreg[i];
            }
        }
    };

    issue(0);
    for (int dnk = 0; dnk < nk; ++dnk) {
        commit();
        __syncthreads();
        if (dnk + 1 < nk) issue(dnk + 1);
        if (wt == 1 || dnk < nk - 1) {
            f32x4 st[4] = {};
#pragma unroll
            for (int ks = 0; ks < 3; ks++) {
#pragma unroll
                for (int ct = 0; ct < 4; ct++) {
                    bf16x8 kf = __builtin_bit_cast(bf16x8,
                        *reinterpret_cast<const u32x4*>(&Ks[ct * 16 + lr][ks * 32 + lg * 8]));
                    st[ct] = __builtin_amdgcn_mfma_f32_16x16x32_bf16(kf, qf[ks], st[ct], 0, 0, 0);
                }
            }
            float mx = st[0][0];
#pragma unroll
            for (int ct = 0; ct < 4; ct++)
#pragma unroll
                for (int rr = 0; rr < 4; rr++) mx = fmaxf(mx, st[ct][rr]);
            mx = fmaxf(mx, __shfl_xor(mx, 16));
            mx = fmaxf(mx, __shfl_xor(mx, 32));
            float mnew = fmaxf(m_, mx);
            float corr = __expf(m_ - mnew);
            m_ = mnew;
            float ps = 0.f;
#pragma unroll
            for (int ct = 0; ct < 4; ct++) {
                u16x4 pk;
#pragma unroll
                for (int rr = 0; rr < 4; rr++) {
                    float pv = __expf(st[ct][rr] - mnew);
                    ps += pv;
                    pk[rr] = f2bf(pv);
                }
                *reinterpret_cast<u16x4*>(&Ps[wv][lr][ct * 16 + lg * 4]) = pk;
            }
            ps += __shfl_xor(ps, 16);
            ps += __shfl_xor(ps, 32);
            lsum = lsum * corr + ps;
#pragma unroll
            for (int rr = 0; rr < 4; rr++) {
                float cr = __shfl(corr, (lane & 48) | (lg * 4 + rr));
#pragma unroll
                for (int nf = 0; nf < 6; nf++) o[nf][rr] *= cr;
            }
#pragma unroll
            for (int kk = 0; kk < 2; kk++) {
                bf16x8 pf = __builtin_bit_cast(bf16x8,
                    *reinterpret_cast<const u32x4*>(&Ps[wv][lr][kk * 32 + lg * 8]));
#pragma unroll
                for (int nf = 0; nf < 6; nf++) {
                    bf16x8 vf = __builtin_bit_cast(bf16x8,
                        *reinterpret_cast<const u32x4*>(&Vs[nf * 16 + lr][kk * 32 + lg * 8]));
                    o[nf] = __builtin_amdgcn_mfma_f32_16x16x32_bf16(pf, vf, o[nf], 0, 0, 0);
                }
            }
        }
        __syncthreads();
    }

#pragma unroll
    for (int rr = 0; rr < 4; rr++) {
        float li = __shfl(lsum, (lane & 48) | (lg * 4 + rr));
        float inv = 1.f / li;
        size_t row = qrow0 + wq * 16 + lg * 4 + rr;
#pragma unroll
        for (int nf = 0; nf < 6; nf++)
            aout[row * 192 + head * 96 + nf * 16 + lr] = f2bf(o[nf][rr] * inv);
    }
}

// ---------------------------------------------------------------------------
// Launcher. ws arena (~341 MB) with aggressive aliasing:
//   [0, 226.5M)        phase A: qk[0,113.2M) + vt[113.2,169.9) + attn[169.9,226.5)
//                      phase B (after oproj): hidden bf16 [147456][768] (226.5M)
//   [226.5M, 283.1M)   ybf bf16
//   [283.1M, 339.7M)   phase A: h bf16 (ln3 out); phase B: xn4 (aliases h)
//   [339.7M, ~341M)    bf16 weights (gamma-folded) + beffq/beff1 fp32
// d_out written only by fc2 (fully rewritten each call => replay safe).
// ---------------------------------------------------------------------------
extern "C" void kernel_launch(void* const* d_in, const int* in_sizes, int n_in,
                              void* d_out, int out_size, void* d_ws, size_t ws_size,
                              hipStream_t stream) {
    const float* x    = (const float*)d_in[0];
    const float* n3g  = (const float*)d_in[1];
    const float* n3b  = (const float*)d_in[2];
    const float* wqkv = (const float*)d_in[3];
    const float* bqkv = (const float*)d_in[4];
    const float* wout = (const float*)d_in[5];
    const float* bout = (const float*)d_in[6];
    const float* n4g  = (const float*)d_in[7];
    const float* n4b  = (const float*)d_in[8];
    const float* wfc1 = (const float*)d_in[9];
    const float* bfc1 = (const float*)d_in[10];
    const float* wfc2 = (const float*)d_in[11];
    const float* bfc2 = (const float*)d_in[12];
    float* out = (float*)d_out;

    char* ws = (char*)d_ws;
    unsigned short* qk     = (unsigned short*)(ws + 0);
    unsigned short* vt     = (unsigned short*)(ws + 113246208);
    unsigned short* attn   = (unsigned short*)(ws + 169869312);
    unsigned short* hidden = (unsigned short*)(ws + 0);           // aliases qk+vt+attn
    unsigned short* ybf    = (unsigned short*)(ws + 226492416);
    unsigned short* h      = (unsigned short*)(ws + 283115520);
    unsigned short* xn4    = (unsigned short*)(ws + 283115520);   // aliases h
    unsigned short* wq_bf  = (unsigned short*)(ws + 339738624);
    unsigned short* wo_bf  = (unsigned short*)(ws + 339984384);
    unsigned short* w1_bf  = (unsigned short*)(ws + 340082688);
    unsigned short* w2_bf  = (unsigned short*)(ws + 340377600);
    float*          beffq  = (float*)(ws + 340770816);
    float*          beff1  = (float*)(ws + 340773120);

    k_wconv<<<2016, 256, 0, stream>>>(wqkv, wout, wfc1, wfc2, n3g, n4g, wq_bf, wo_bf, w1_bf, w2_bf);
    k_bias<<<336, 256, 0, stream>>>(wqkv, bqkv, n3b, wfc1, bfc1, n4b, beffq, beff1);
    k_ln3<<<36864, 256, 0, stream>>>(x, h);
    k_gemm128<0, 192, 4><<<dim3(5, 1152), 256, 0, stream>>>(h, wq_bf, beffq, qk, vt, nullptr, nullptr, nullptr);
    k_attn<<<2304, 512, 0, stream>>>(qk, vt, attn);
    k_gemm128<1, 192, 3><<<dim3(2, 1152), 256, 0, stream>>>(attn, wo_bf, bout, ybf, nullptr, x, nullptr, nullptr);
    k_ln4b<<<18432, 256, 0, stream>>>(ybf, xn4);
    k_gemm128<2, 192, 4><<<dim3(6, 1152), 256, 0, stream>>>(xn4, w1_bf, beff1, hidden, nullptr, nullptr, nullptr, nullptr);
    k_gemm128<3, 768, 3><<<dim3(2, 1152), 256, 0, stream>>>(hidden, w2_bf, bfc2, nullptr, nullptr, nullptr, ybf, out);
}

// Round 14
// 545.819 us; speedup vs baseline: 1.4079x; 1.0102x over previous
//
#include <hip/hip_runtime.h>
#include <cstdint>
#include <cstddef>

// ---------------------------------------------------------------------------
// Shapes: x (2,8,96,96,192) fp32 ; windows 1x8x8 ; NH=2 ; hd=96 ; L=512 ; MLP 768
// tokens N = 147456 ; Bp = 288 ; Dn = 8
// ---------------------------------------------------------------------------

typedef float   f32x4  __attribute__((ext_vector_type(4)));
typedef __bf16  bf16x8 __attribute__((ext_vector_type(8)));
typedef unsigned int   u32x4  __attribute__((ext_vector_type(4)));
typedef unsigned short u16x4  __attribute__((ext_vector_type(4)));

#define DEVI __device__ __forceinline__

DEVI float bf2f(unsigned short u) {
    union { unsigned int i; float f; } v; v.i = ((unsigned int)u) << 16; return v.f;
}
DEVI unsigned short f2bf(float f) {
    unsigned int u = __builtin_bit_cast(unsigned int, f);
    unsigned int r = u + 0x7fffu + ((u >> 16) & 1u);   // RNE
    return (unsigned short)(r >> 16);
}
// tanh-form GELU via one v_exp (passed at 0.03125 since round 7)
DEVI float gelu_fast(float v) {
    float t = v * v;
    float z = v * (1.5957691216057308f + 0.07135481627f * t);
    float e = __expf(z);
    float r = 2.0f / (1.0f + e);
    return v - 0.5f * v * r;
}
// pack 4 f32 -> 4 fp8 e4m3 (OCP) in one u32
DEVI unsigned int pk_fp8x4(float a, float b, float c, float d) {
    int v = __builtin_amdgcn_cvt_pk_fp8_f32(a, b, 0, false);
    v = __builtin_amdgcn_cvt_pk_fp8_f32(c, d, v, true);
    return (unsigned int)v;
}
DEVI f32x4 mfma_fp8(unsigned long long a, unsigned long long b, f32x4 c) {
    return __builtin_amdgcn_mfma_f32_16x16x32_fp8_fp8((long)a, (long)b, c, 0, 0, 0);
}

// async global->LDS, 16B per lane; LDS dest is wave-uniform base + lane*16
typedef __attribute__((address_space(3))) unsigned char       lds_u8;
typedef __attribute__((address_space(1))) const unsigned char g_u8;
DEVI void gl_lds16(const void* g, void* l) {
    __builtin_amdgcn_global_load_lds((g_u8*)g, (lds_u8*)l, 16, 0, 0);
}

// ---------------------------------------------------------------------------
// K0: convert + pad weights: wq/wo/w1 -> bf16 (LN gammas folded), w2 -> fp8.
// ---------------------------------------------------------------------------
__global__ __launch_bounds__(256) void k_wconv(const float* __restrict__ wqkv,
                                               const float* __restrict__ wout,
                                               const float* __restrict__ wfc1,
                                               const float* __restrict__ wfc2,
                                               const float* __restrict__ n3g,
                                               const float* __restrict__ n4g,
                                               unsigned short* __restrict__ oq,
                                               unsigned short* __restrict__ oo,
                                               unsigned short* __restrict__ o1,
                                               unsigned short* __restrict__ o2f8) {
    int i = blockIdx.x * 256 + threadIdx.x;
    if (i < 122880) {                       // [640][192] bf16
        int r = i / 192, c = i - r * 192;
        oq[i] = (r < 576) ? f2bf(wqkv[i] * n3g[c]) : (unsigned short)0;
    } else if (i < 172032) {                // [256][192] bf16
        int j = i - 122880; int r = j / 192;
        oo[j] = (r < 192) ? f2bf(wout[j]) : (unsigned short)0;
    } else if (i < 319488) {                // [768][192] bf16
        int j = i - 172032; int c = j % 192;
        o1[j] = f2bf(wfc1[j] * n4g[c]);
    } else if (i < 417792) {                // [256][768] fp8, 2 elems/thread
        int j = i - 319488;                  // pair index over [256][384]
        int r = j / 384;
        float a = 0.f, b = 0.f;
        if (r < 192) { a = wfc2[2 * j]; b = wfc2[2 * j + 1]; }
        int pk = __builtin_amdgcn_cvt_pk_fp8_f32(a, b, 0, false);
        o2f8[j] = (unsigned short)pk;        // o2f8 = fp8 pairs
    }
}

// ---------------------------------------------------------------------------
// K0b: effective biases folding LN beta through the (raw) weights.
// ---------------------------------------------------------------------------
__global__ __launch_bounds__(256) void k_bias(const float* __restrict__ wqkv,
                                              const float* __restrict__ bqkv,
                                              const float* __restrict__ n3b,
                                              const float* __restrict__ wfc1,
                                              const float* __restrict__ bfc1,
                                              const float* __restrict__ n4b,
                                              float* __restrict__ beffq,
                                              float* __restrict__ beff1) {
    int wid = blockIdx.x * 4 + (threadIdx.x >> 6);
    int lane = threadIdx.x & 63;
    const float* wrow; const float* bb; float base; float* dst;
    if (wid < 576) { wrow = wqkv + (size_t)wid * 192; bb = n3b; base = bqkv[wid]; dst = beffq + wid; }
    else { int h = wid - 576; wrow = wfc1 + (size_t)h * 192; bb = n4b; base = bfc1[h]; dst = beff1 + h; }
    float s = wrow[lane] * bb[lane] + wrow[lane + 64] * bb[lane + 64]
            + wrow[lane + 128] * bb[lane + 128];
#pragma unroll
    for (int off = 32; off; off >>= 1) s += __shfl_xor(s, off);
    if (lane == 0) *dst = base + s;
}

// ---------------------------------------------------------------------------
// K1: LayerNorm(norm3) WITHOUT affine + window partition -> h bf16.
// ---------------------------------------------------------------------------
__global__ __launch_bounds__(256) void k_ln3(const float* __restrict__ x,
                                             unsigned short* __restrict__ h) {
    int w = threadIdx.x >> 6, lane = threadIdx.x & 63;
    int token = blockIdx.x * 4 + w;
    const float* xp = x + (size_t)token * 192;
    float v0 = xp[lane], v1 = xp[lane + 64], v2 = xp[lane + 128];
    float s = v0 + v1 + v2;
#pragma unroll
    for (int off = 32; off; off >>= 1) s += __shfl_xor(s, off);
    float mean = s * (1.f / 192.f);
    float d0 = v0 - mean, d1 = v1 - mean, d2 = v2 - mean;
    float q = d0 * d0 + d1 * d1 + d2 * d2;
#pragma unroll
    for (int off = 32; off; off >>= 1) q += __shfl_xor(q, off);
    float rs = rsqrtf(q * (1.f / 192.f) + 1e-5f);
    int b  = token / (8 * 96 * 96);
    int r0 = token - b * (8 * 96 * 96);
    int d  = r0 / (96 * 96);
    int r1 = r0 - d * (96 * 96);
    int hh = r1 / 96;
    int ww = r1 - hh * 96;
    int bp = b * 144 + (hh >> 3) * 12 + (ww >> 3);
    int l  = d * 64 + (hh & 7) * 8 + (ww & 7);
    unsigned short* hp = h + ((size_t)bp * 512 + l) * 192;
    hp[lane]       = f2bf(d0 * rs);
    hp[lane + 64]  = f2bf(d1 * rs);
    hp[lane + 128] = f2bf(d2 * rs);
}

// ---------------------------------------------------------------------------
// K2: 128xBN GEMM (BN = NF*32), dbuf + counted-vmcnt (unchanged from R13).
// EPI 0 (NF=4): qkv -> qk (q scaled) + vt ; EPI 1 (NF=3): out_proj -> ybf.
// ---------------------------------------------------------------------------
template <int EPI, int K, int NF>
__global__ __launch_bounds__(256) void k_gemm128(const unsigned short* __restrict__ A,
                                                 const unsigned short* __restrict__ Bw,
                                                 const float* __restrict__ bias,
                                                 unsigned short* __restrict__ outb,
                                                 unsigned short* __restrict__ vt,
                                                 const float* __restrict__ res) {
    __shared__ unsigned short As[2][128 * 64];
    __shared__ unsigned short Bs[2][NF * 32 * 64];
    const int tid = threadIdx.x;
    const int nwg = gridDim.x * gridDim.y;
    const int flat = blockIdx.y * gridDim.x + blockIdx.x;
    const int swz = (flat & 7) * (nwg >> 3) + (flat >> 3);
    const int bx = swz % gridDim.x, by = swz / gridDim.x;
    const int row0 = by * 128, col0 = bx * (NF * 32);
    const int wv = tid >> 6, lane = tid & 63, lr = lane & 15, lg = lane >> 4;
    const int wr = wv >> 1, wc = wv & 1;
    const int sr = lane >> 3, sc = lane & 7;
    f32x4 acc[4][NF] = {};

    auto stage = [&](int t, int buf) {
        int k0 = t * 64;
#pragma unroll
        for (int i = 0; i < 4; i++) {
            int gq = wv * 4 + i;
            int r = gq * 8 + sr;
            int j = sc ^ (r & 7);
            gl_lds16(A + (size_t)(row0 + r) * K + k0 + j * 8, &As[buf][gq * 512]);
        }
#pragma unroll
        for (int i = 0; i < NF; i++) {
            int gq = wv * NF + i;
            int r = gq * 8 + sr;
            int j = sc ^ (r & 7);
            gl_lds16(Bw + (size_t)(col0 + r) * K + k0 + j * 8, &Bs[buf][gq * 512]);
        }
    };

    const int NT = K / 64;
    stage(0, 0);
    for (int t = 0; t < NT; ++t) {
        int cur = t & 1;
        if (t + 1 < NT) {
            stage(t + 1, cur ^ 1);
            if constexpr (NF == 4) asm volatile("s_waitcnt vmcnt(8)" ::: "memory");
            else                   asm volatile("s_waitcnt vmcnt(7)" ::: "memory");
        } else {
            asm volatile("s_waitcnt vmcnt(0)" ::: "memory");
        }
        __builtin_amdgcn_sched_barrier(0);
        __builtin_amdgcn_s_barrier();
        __builtin_amdgcn_sched_barrier(0);
#pragma unroll
        for (int kk = 0; kk < 64; kk += 32) {
            bf16x8 af[4], bf[NF];
#pragma unroll
            for (int m = 0; m < 4; m++) {
                int r = wr * 64 + m * 16 + lr;
                int j = ((kk >> 3) + lg) ^ (r & 7);
                af[m] = __builtin_bit_cast(bf16x8,
                    *reinterpret_cast<const u32x4*>(&As[cur][r * 64 + j * 8]));
            }
#pragma unroll
            for (int n = 0; n < NF; n++) {
                int r = wc * (NF * 16) + n * 16 + lr;
                int j = ((kk >> 3) + lg) ^ (r & 7);
                bf[n] = __builtin_bit_cast(bf16x8,
                    *reinterpret_cast<const u32x4*>(&Bs[cur][r * 64 + j * 8]));
            }
#pragma unroll
            for (int m = 0; m < 4; m++)
#pragma unroll
                for (int n = 0; n < NF; n++)
                    acc[m][n] = __builtin_amdgcn_mfma_f32_16x16x32_bf16(bf[n], af[m], acc[m][n], 0, 0, 0);
        }
        __builtin_amdgcn_sched_barrier(0);
        __builtin_amdgcn_s_barrier();
        __builtin_amdgcn_sched_barrier(0);
    }

#pragma unroll
    for (int m = 0; m < 4; m++) {
        const int arow = row0 + wr * 64 + m * 16 + lr;
        if constexpr (EPI == 0) {
#pragma unroll
            for (int n = 0; n < NF; n++) {
                const int colb = col0 + wc * (NF * 16) + n * 16 + lg * 4;
                if (colb < 384) {
                    f32x4 b4 = *reinterpret_cast<const f32x4*>(bias + colb);
                    float sc2 = (colb < 192) ? 0.1020620726159658f : 1.f;  // 1/sqrt(96) on q
                    u16x4 pk;
#pragma unroll
                    for (int rr = 0; rr < 4; rr++) pk[rr] = f2bf((acc[m][n][rr] + b4[rr]) * sc2);
                    *reinterpret_cast<u16x4*>(outb + (size_t)arow * 384 + colb) = pk;
                } else if (colb < 576) {
                    int head = (colb >= 480) ? 1 : 0;
                    int bp = arow >> 9, tok = arow & 511;
                    size_t vb = ((size_t)(bp * 2 + head) * 96 + (colb - 384 - head * 96)) * 512 + tok;
#pragma unroll
                    for (int rr = 0; rr < 4; rr++)
                        vt[vb + (size_t)rr * 512] = f2bf(acc[m][n][rr] + bias[colb + rr]);
                }
            }
        } else {
            int bp = arow >> 9, l = arow & 511;
            int bb = bp / 144, p = bp - bb * 144;
            int hn = p / 12, wn = p - hn * 12;
            int dn = l >> 6, t_ = l & 63;
            size_t tok = ((size_t)((bb * 8 + dn) * 96 + hn * 8 + (t_ >> 3)) * 96 + wn * 8 + (t_ & 7));
#pragma unroll
            for (int n = 0; n < NF; n++) {
                const int colb = col0 + wc * (NF * 16) + n * 16 + lg * 4;   // < 192
                size_t idx = tok * 192 + colb;
                f32x4 r4 = *reinterpret_cast<const f32x4*>(res + idx);
                f32x4 b4 = *reinterpret_cast<const f32x4*>(bias + colb);
                u16x4 pk;
#pragma unroll
                for (int rr = 0; rr < 4; rr++) pk[rr] = f2bf(r4[rr] + acc[m][n][rr] + b4[rr]);
                *reinterpret_cast<u16x4*>(outb + idx) = pk;
            }
        }
    }
}

// ---------------------------------------------------------------------------
// K3: block-causal attention (unchanged).
// ---------------------------------------------------------------------------
__global__ __launch_bounds__(512) void k_attn(const unsigned short* __restrict__ qk,
                                              const unsigned short* __restrict__ vt,
                                              unsigned short* __restrict__ aout) {
    __shared__ unsigned short Ks[64][104];
    __shared__ unsigned short Vs[96][72];
    __shared__ unsigned short Ps[8][16][72];

    int bid = (blockIdx.x & 7) * 288 + (blockIdx.x >> 3);
    int bp = bid >> 3, rest = bid & 7, head = rest >> 2, pr = rest & 3;
    int tid = threadIdx.x, wv = tid >> 6, lane = tid & 63;
    int lr = lane & 15, lg = lane >> 4;
    int wq = wv & 3, wt = wv >> 2;
    int nk = 2 * pr + 2;

    size_t qrow0 = (size_t)bp * 512 + (size_t)(2 * pr + wt) * 64;
    const unsigned short* vbase = vt + (size_t)(bp * 2 + head) * 96 * 512;
    size_t krowb = (size_t)bp * 512;

    bf16x8 qf[3];
    {
        const unsigned short* qp = qk + (qrow0 + wq * 16 + lr) * 384 + head * 96 + lg * 8;
#pragma unroll
        for (int ks = 0; ks < 3; ks++)
            qf[ks] = __builtin_bit_cast(bf16x8, *reinterpret_cast<const u32x4*>(qp + ks * 32));
    }

    f32x4 o[6] = {};
    float m_ = -1e30f, lsum = 0.f;

    u32x4 sreg[3];
    auto issue = [&](int dnk) {
#pragma unroll
        for (int i = 0; i < 3; i++) {
            int c = tid + i * 512;
            if (c < 768) {
                int r = c / 12, cc = c - r * 12;
                sreg[i] = *reinterpret_cast<const u32x4*>(
                    qk + (krowb + dnk * 64 + r) * 384 + 192 + head * 96 + cc * 8);
            } else {
                int c2 = c - 768; int d = c2 >> 3, tb = c2 & 7;
                sreg[i] = *reinterpret_cast<const u32x4*>(
                    vbase + (size_t)d * 512 + dnk * 64 + tb * 8);
            }
        }
    };
    auto commit = [&]() {
#pragma unroll
        for (int i = 0; i < 3; i++) {
            int c = tid + i * 512;
            if (c < 768) {
                int r = c / 12, cc = c - r * 12;
                *reinterpret_cast<u32x4*>(&Ks[r][cc * 8]) = sreg[i];
            } else {
                int c2 = c - 768; int d = c2 >> 3, tb = c2 & 7;
                *reinterpret_cast<u32x4*>(&Vs[d][tb * 8]) = sreg[i];
            }
        }
    };

    issue(0);
    for (int dnk = 0; dnk < nk; ++dnk) {
        commit();
        __syncthreads();
        if (dnk + 1 < nk) issue(dnk + 1);
        if (wt == 1 || dnk < nk - 1) {
            f32x4 st[4] = {};
#pragma unroll
            for (int ks = 0; ks < 3; ks++) {
#pragma unroll
                for (int ct = 0; ct < 4; ct++) {
                    bf16x8 kf = __builtin_bit_cast(bf16x8,
                        *reinterpret_cast<const u32x4*>(&Ks[ct * 16 + lr][ks * 32 + lg * 8]));
                    st[ct] = __builtin_amdgcn_mfma_f32_16x16x32_bf16(kf, qf[ks], st[ct], 0, 0, 0);
                }
            }
            float mx = st[0][0];
#pragma unroll
            for (int ct = 0; ct < 4; ct++)
#pragma unroll
                for (int rr = 0; rr < 4; rr++) mx = fmaxf(mx, st[ct][rr]);
            mx = fmaxf(mx, __shfl_xor(mx, 16));
            mx = fmaxf(mx, __shfl_xor(mx, 32));
            float mnew = fmaxf(m_, mx);
            float corr = __expf(m_ - mnew);
            m_ = mnew;
            float ps = 0.f;
#pragma unroll
            for (int ct = 0; ct < 4; ct++) {
                u16x4 pk;
#pragma unroll
                for (int rr = 0; rr < 4; rr++) {
                    float pv = __expf(st[ct][rr] - mnew);
                    ps += pv;
                    pk[rr] = f2bf(pv);
                }
                *reinterpret_cast<u16x4*>(&Ps[wv][lr][ct * 16 + lg * 4]) = pk;
            }
            ps += __shfl_xor(ps, 16);
            ps += __shfl_xor(ps, 32);
            lsum = lsum * corr + ps;
#pragma unroll
            for (int rr = 0; rr < 4; rr++) {
                float cr = __shfl(corr, (lane & 48) | (lg * 4 + rr));
#pragma unroll
                for (int nf = 0; nf < 6; nf++) o[nf][rr] *= cr;
            }
#pragma unroll
            for (int kk = 0; kk < 2; kk++) {
                bf16x8 pf = __builtin_bit_cast(bf16x8,
                    *reinterpret_cast<const u32x4*>(&Ps[wv][lr][kk * 32 + lg * 8]));
#pragma unroll
                for (int nf = 0; nf < 6; nf++) {
                    bf16x8 vf = __builtin_bit_cast(bf16x8,
                        *reinterpret_cast<const u32x4*>(&Vs[nf * 16 + lr][kk * 32 + lg * 8]));
                    o[nf] = __builtin_amdgcn_mfma_f32_16x16x32_bf16(pf, vf, o[nf], 0, 0, 0);
                }
            }
        }
        __syncthreads();
    }

#pragma unroll
    for (int rr = 0; rr < 4; rr++) {
        float li = __shfl(lsum, (lane & 48) | (lg * 4 + rr));
        float inv = 1.f / li;
        size_t row = qrow0 + wq * 16 + lg * 4 + rr;
#pragma unroll
        for (int nf = 0; nf < 6; nf++)
            aout[row * 192 + head * 96 + nf * 16 + lr] = f2bf(o[nf][rr] * inv);
    }
}

// ---------------------------------------------------------------------------
// K4: fc1 with FUSED LN4 (reg-staged A from ybf, k_qkv pattern) + gelu ->
// hidden fp8 [147456][768]. 128x128 tile, grid (6,1152), LDS 80 KB.
// ---------------------------------------------------------------------------
__global__ __launch_bounds__(256) void k_fc1(const unsigned short* __restrict__ ybf,
                                             const unsigned short* __restrict__ w1,
                                             const float* __restrict__ beff1,
                                             unsigned char* __restrict__ hid) {
    __shared__ unsigned short As[3][128][64];    // 48 KB
    __shared__ unsigned short Bs[2][128 * 64];   // 32 KB
    const int tid = threadIdx.x;
    const int nwg = gridDim.x * gridDim.y;
    const int flat = blockIdx.y * gridDim.x + blockIdx.x;
    const int swz = (flat & 7) * (nwg >> 3) + (flat >> 3);
    const int bx = swz % gridDim.x, by = swz / gridDim.x;
    const int row0 = by * 128, col0 = bx * 128;
    const int wv = tid >> 6, lane = tid & 63, lr = lane & 15, lg = lane >> 4;
    const int wr = wv >> 1, wc = wv & 1;
    const int sr = lane >> 3, sc = lane & 7;

    auto stageB = [&](int t, int buf) {
        int k0 = t * 64;
#pragma unroll
        for (int i = 0; i < 4; i++) {
            int gq = wv * 4 + i;
            int r = gq * 8 + sr;
            int j = sc ^ (r & 7);
            gl_lds16(w1 + (size_t)(col0 + r) * 192 + k0 + j * 8, &Bs[buf][gq * 512]);
        }
    };

    stageB(0, 0);
    // --- reg-stage A from ybf (bf16) + exact fp32 LN4 stats + normalize ---
    {
        int ar = tid >> 1, ah = tid & 1;          // 2 threads/row, 12 chunks each
        const unsigned short* src = ybf + (size_t)(row0 + ar) * 192;
        float sum = 0.f, ssq = 0.f;
#pragma unroll
        for (int ci = 0; ci < 12; ci++) {
            int c = ah * 12 + ci;
            u32x4 v = *reinterpret_cast<const u32x4*>(src + c * 8);
            u16x4* hv = reinterpret_cast<u16x4*>(&v);
#pragma unroll
            for (int e = 0; e < 8; e++) {
                float f = bf2f(((unsigned short*)&v)[e]);
                sum += f; ssq += f * f;
            }
            (void)hv;
            int j = (c & 7) ^ (ar & 7);
            *reinterpret_cast<u32x4*>(&As[c >> 3][ar][j * 8]) = v;
        }
        sum += __shfl_xor(sum, 1); ssq += __shfl_xor(ssq, 1);
        float mu = sum * (1.f / 192.f);
        float rs = rsqrtf(ssq * (1.f / 192.f) - mu * mu + 1e-5f);
#pragma unroll
        for (int ci = 0; ci < 12; ci++) {
            int c = ah * 12 + ci;
            int j = (c & 7) ^ (ar & 7);
            unsigned short* p8 = &As[c >> 3][ar][j * 8];
#pragma unroll
            for (int e = 0; e < 8; e++)
                p8[e] = f2bf((bf2f(p8[e]) - mu) * rs);
        }
    }
    asm volatile("s_waitcnt lgkmcnt(0)" ::: "memory");   // normalize writes drained

    f32x4 acc[4][4] = {};
#pragma unroll
    for (int t = 0; t < 3; ++t) {
        if (t + 1 < 3) {
            stageB(t + 1, (t + 1) & 1);
            asm volatile("s_waitcnt vmcnt(4)" ::: "memory");
        } else {
            asm volatile("s_waitcnt vmcnt(0)" ::: "memory");
        }
        __builtin_amdgcn_sched_barrier(0);
        __builtin_amdgcn_s_barrier();
        __builtin_amdgcn_sched_barrier(0);
#pragma unroll
        for (int kk = 0; kk < 64; kk += 32) {
            bf16x8 af[4], bf[4];
#pragma unroll
            for (int m = 0; m < 4; m++) {
                int r = wr * 64 + m * 16 + lr;
                int j = ((kk >> 3) + lg) ^ (r & 7);
                af[m] = __builtin_bit_cast(bf16x8,
                    *reinterpret_cast<const u32x4*>(&As[t][r][j * 8]));
            }
#pragma unroll
            for (int n = 0; n < 4; n++) {
                int r = wc * 64 + n * 16 + lr;
                int j = ((kk >> 3) + lg) ^ (r & 7);
                bf[n] = __builtin_bit_cast(bf16x8,
                    *reinterpret_cast<const u32x4*>(&Bs[t & 1][r * 64 + j * 8]));
            }
#pragma unroll
            for (int m = 0; m < 4; m++)
#pragma unroll
                for (int n = 0; n < 4; n++)
                    acc[m][n] = __builtin_amdgcn_mfma_f32_16x16x32_bf16(bf[n], af[m], acc[m][n], 0, 0, 0);
        }
        __builtin_amdgcn_sched_barrier(0);
        __builtin_amdgcn_s_barrier();
        __builtin_amdgcn_sched_barrier(0);
    }

    // epilogue: gelu + fp8 pack (u32 = 4 cols) -> hidden
#pragma unroll
    for (int m = 0; m < 4; m++) {
        const int arow = row0 + wr * 64 + m * 16 + lr;
#pragma unroll
        for (int n = 0; n < 4; n++) {
            const int colb = col0 + wc * 64 + n * 16 + lg * 4;   // < 768
            f32x4 b4 = *reinterpret_cast<const f32x4*>(beff1 + colb);
            float g0 = gelu_fast(acc[m][n][0] + b4[0]);
            float g1 = gelu_fast(acc[m][n][1] + b4[1]);
            float g2 = gelu_fast(acc[m][n][2] + b4[2]);
            float g3 = gelu_fast(acc[m][n][3] + b4[3]);
            *reinterpret_cast<unsigned int*>(hid + (size_t)arow * 768 + colb) =
                pk_fp8x4(g0, g1, g2, g3);
        }
    }
}

// ---------------------------------------------------------------------------
// K5: fc2 as fp8 x fp8 GEMM: out = hidden(fp8) @ w2(fp8)^T + b2 + ybf.
// 128x96 tile (NF=3), K=768 (12 k-tiles), LDS 32 KB (2x8KB A + 2x8KB B).
// Chunk = 16 fp8 (16B); swizzle j = ch ^ (r&3). mfma_f32_16x16x32_fp8_fp8.
// ---------------------------------------------------------------------------
__global__ __launch_bounds__(256) void k_fc2(const unsigned char* __restrict__ hid,
                                             const unsigned char* __restrict__ w2,
                                             const float* __restrict__ b2,
                                             const unsigned short* __restrict__ ybf,
                                             float* __restrict__ out) {
    __shared__ unsigned char As[2][128 * 64];    // 16 KB
    __shared__ unsigned char Bs[2][128 * 64];    // 16 KB
    const int tid = threadIdx.x;
    const int nwg = gridDim.x * gridDim.y;
    const int flat = blockIdx.y * gridDim.x + blockIdx.x;
    const int swz = (flat & 7) * (nwg >> 3) + (flat >> 3);
    const int bx = swz % gridDim.x, by = swz / gridDim.x;
    const int row0 = by * 128, col0 = bx * 96;
    const int wv = tid >> 6, lane = tid & 63, lr = lane & 15, lg = lane >> 4;
    const int wr = wv >> 1, wc = wv & 1;
    const int sr4 = lane >> 2, sc4 = lane & 3;   // 16 rows x 4 chunks per 1KB group
    f32x4 acc[4][3] = {};

    auto stage = [&](int t, int buf) {
        int k0 = t * 64;
#pragma unroll
        for (int i = 0; i < 2; i++) {
            int g = wv * 2 + i;                  // 8 groups of 16 rows
            int r = g * 16 + sr4;
            int j = sc4 ^ (r & 3);
            gl_lds16(hid + (size_t)(row0 + r) * 768 + k0 + j * 16, &As[buf][g * 1024]);
        }
#pragma unroll
        for (int i = 0; i < 2; i++) {
            int g = wv * 2 + i;
            int r = g * 16 + sr4;                // stage 128 weight rows (96 used)
            int j = sc4 ^ (r & 3);
            gl_lds16(w2 + (size_t)(col0 + r) * 768 + k0 + j * 16, &Bs[buf][g * 1024]);
        }
    };

    stage(0, 0);
    for (int t = 0; t < 12; ++t) {
        int cur = t & 1;
        if (t + 1 < 12) {
            stage(t + 1, cur ^ 1);
            asm volatile("s_waitcnt vmcnt(4)" ::: "memory");
        } else {
            asm volatile("s_waitcnt vmcnt(0)" ::: "memory");
        }
        __builtin_amdgcn_sched_barrier(0);
        __builtin_amdgcn_s_barrier();
        __builtin_amdgcn_sched_barrier(0);
#pragma unroll
        for (int kk = 0; kk < 2; kk++) {
            const int cc = kk * 2 + (lg >> 1);   // 16B chunk index of this frag
            const int off = (lg & 1) * 8;
            unsigned long long af[4], bfr[3];
#pragma unroll
            for (int m = 0; m < 4; m++) {
                int r = wr * 64 + m * 16 + lr;
                int j = cc ^ (r & 3);
                af[m] = *reinterpret_cast<const unsigned long long*>(
                    &As[cur][r * 64 + j * 16 + off]);
            }
#pragma unroll
            for (int n = 0; n < 3; n++) {
                int r = wc * 48 + n * 16 + lr;
                int j = cc ^ (r & 3);
                bfr[n] = *reinterpret_cast<const unsigned long long*>(
                    &Bs[cur][r * 64 + j * 16 + off]);
            }
#pragma unroll
            for (int m = 0; m < 4; m++)
#pragma unroll
                for (int n = 0; n < 3; n++)
                    acc[m][n] = mfma_fp8(bfr[n], af[m], acc[m][n]);
        }
        __builtin_amdgcn_sched_barrier(0);
        __builtin_amdgcn_s_barrier();
        __builtin_amdgcn_sched_barrier(0);
    }

    // epilogue: bias + ybf residual -> fp32 out
#pragma unroll
    for (int m = 0; m < 4; m++) {
        const int arow = row0 + wr * 64 + m * 16 + lr;
#pragma unroll
        for (int n = 0; n < 3; n++) {
            const int colb = col0 + wc * 48 + n * 16 + lg * 4;   // < 192
            size_t idx = (size_t)arow * 192 + colb;
            f32x4 b4 = *reinterpret_cast<const f32x4*>(b2 + colb);
            u16x4 rb = *reinterpret_cast<const u16x4*>(ybf + idx);
            f32x4 o4;
#pragma unroll
            for (int rr = 0; rr < 4; rr++) o4[rr] = bf2f(rb[rr]) + acc[m][n][rr] + b4[rr];
            *reinterpret_cast<f32x4*>(out + idx) = o4;
        }
    }
}

// ---------------------------------------------------------------------------
// Launcher. ws arena (~341 MB):
//   [0, 113.2M)        phase A: qk bf16 ; phase B: hidden fp8 [147456][768]
//   [113.2M, 169.9M)   vt bf16
//   [169.9M, 226.5M)   attn bf16
//   [226.5M, 283.1M)   ybf bf16
//   [283.1M, 339.7M)   h bf16 (ln3 out)
//   [339.7M, ~341M)    weights (wq/wo/w1 bf16 gamma-folded, w2 fp8) + biases
// d_out written only by k_fc2 (fully rewritten each call => replay safe).
// ---------------------------------------------------------------------------
extern "C" void kernel_launch(void* const* d_in, const int* in_sizes, int n_in,
                              void* d_out, int out_size, void* d_ws, size_t ws_size,
                              hipStream_t stream) {
    const float* x    = (const float*)d_in[0];
    const float* n3g  = (const float*)d_in[1];
    const float* n3b  = (const float*)d_in[2];
    const float* wqkv = (const float*)d_in[3];
    const float* bqkv = (const float*)d_in[4];
    const float* wout = (const float*)d_in[5];
    const float* bout = (const float*)d_in[6];
    const float* n4g  = (const float*)d_in[7];
    const float* n4b  = (const float*)d_in[8];
    const float* wfc1 = (const float*)d_in[9];
    const float* bfc1 = (const float*)d_in[10];
    const float* wfc2 = (const float*)d_in[11];
    const float* bfc2 = (const float*)d_in[12];
    float* out = (float*)d_out;

    char* ws = (char*)d_ws;
    unsigned short* qk     = (unsigned short*)(ws + 0);
    unsigned char*  hidden = (unsigned char*)(ws + 0);            // aliases qk (dead)
    unsigned short* vt     = (unsigned short*)(ws + 113246208);
    unsigned short* attn   = (unsigned short*)(ws + 169869312);
    unsigned short* ybf    = (unsigned short*)(ws + 226492416);
    unsigned short* h      = (unsigned short*)(ws + 283115520);
    unsigned short* wq_bf  = (unsigned short*)(ws + 339738624);
    unsigned short* wo_bf  = (unsigned short*)(ws + 339984384);
    unsigned short* w1_bf  = (unsigned short*)(ws + 340082688);
    unsigned short* w2_f8p = (unsigned short*)(ws + 340377600);   // fp8 pairs
    unsigned char*  w2_f8  = (unsigned char*)(ws + 340377600);
    float*          beffq  = (float*)(ws + 340574208);
    float*          beff1  = (float*)(ws + 340576512);

    k_wconv<<<1632, 256, 0, stream>>>(wqkv, wout, wfc1, wfc2, n3g, n4g, wq_bf, wo_bf, w1_bf, w2_f8p);
    k_bias<<<336, 256, 0, stream>>>(wqkv, bqkv, n3b, wfc1, bfc1, n4b, beffq, beff1);
    k_ln3<<<36864, 256, 0, stream>>>(x, h);
    k_gemm128<0, 192, 4><<<dim3(5, 1152), 256, 0, stream>>>(h, wq_bf, beffq, qk, vt, nullptr);
    k_attn<<<2304, 512, 0, stream>>>(qk, vt, attn);
    k_gemm128<1, 192, 3><<<dim3(2, 1152), 256, 0, stream>>>(attn, wo_bf, bout, ybf, nullptr, x);
    k_fc1<<<dim3(6, 1152), 256, 0, stream>>>(ybf, w1_bf, beff1, hidden);
    k_fc2<<<dim3(2, 1152), 256, 0, stream>>>(hidden, w2_f8, bfc2, ybf, out);
}

// Round 15
// 513.580 us; speedup vs baseline: 1.4963x; 1.0628x over previous
//
#include <hip/hip_runtime.h>
#include <cstdint>
#include <cstddef>

// ---------------------------------------------------------------------------
// Shapes: x (2,8,96,96,192) fp32 ; windows 1x8x8 ; NH=2 ; hd=96 ; L=512 ; MLP 768
// tokens N = 147456 ; Bp = 288 ; Dn = 8
// ---------------------------------------------------------------------------

typedef float   f32x4  __attribute__((ext_vector_type(4)));
typedef __bf16  bf16x8 __attribute__((ext_vector_type(8)));
typedef unsigned int   u32x4  __attribute__((ext_vector_type(4)));
typedef unsigned short u16x4  __attribute__((ext_vector_type(4)));

#define DEVI __device__ __forceinline__

DEVI float bf2f(unsigned short u) {
    union { unsigned int i; float f; } v; v.i = ((unsigned int)u) << 16; return v.f;
}
DEVI unsigned short f2bf(float f) {
    unsigned int u = __builtin_bit_cast(unsigned int, f);
    unsigned int r = u + 0x7fffu + ((u >> 16) & 1u);   // RNE
    return (unsigned short)(r >> 16);
}
// sigmoid-form GELU: v * sigmoid(1.702 v). |err vs erf-gelu| <= ~0.02, below
// the fp8 e4m3 quantization noise already absorbed (absmax unchanged 0.03125).
DEVI float gelu_sig(float v) {
    float e = __expf(-1.702f * v);
    return v * __builtin_amdgcn_rcpf(1.f + e);
}
// pack 4 f32 -> 4 fp8 e4m3 (OCP) in one u32
DEVI unsigned int pk_fp8x4(float a, float b, float c, float d) {
    int v = __builtin_amdgcn_cvt_pk_fp8_f32(a, b, 0, false);
    v = __builtin_amdgcn_cvt_pk_fp8_f32(c, d, v, true);
    return (unsigned int)v;
}
DEVI f32x4 mfma_fp8(unsigned long long a, unsigned long long b, f32x4 c) {
    return __builtin_amdgcn_mfma_f32_16x16x32_fp8_fp8((long)a, (long)b, c, 0, 0, 0);
}

// async global->LDS, 16B per lane; LDS dest is wave-uniform base + lane*16
typedef __attribute__((address_space(3))) unsigned char       lds_u8;
typedef __attribute__((address_space(1))) const unsigned char g_u8;
DEVI void gl_lds16(const void* g, void* l) {
    __builtin_amdgcn_global_load_lds((g_u8*)g, (lds_u8*)l, 16, 0, 0);
}

// ---------------------------------------------------------------------------
// K0: convert + pad weights: wq/wo/w1 -> bf16 (LN gammas folded), w2 -> fp8.
// ---------------------------------------------------------------------------
__global__ __launch_bounds__(256) void k_wconv(const float* __restrict__ wqkv,
                                               const float* __restrict__ wout,
                                               const float* __restrict__ wfc1,
                                               const float* __restrict__ wfc2,
                                               const float* __restrict__ n3g,
                                               const float* __restrict__ n4g,
                                               unsigned short* __restrict__ oq,
                                               unsigned short* __restrict__ oo,
                                               unsigned short* __restrict__ o1,
                                               unsigned short* __restrict__ o2f8) {
    int i = blockIdx.x * 256 + threadIdx.x;
    if (i < 122880) {                       // [640][192] bf16
        int r = i / 192, c = i - r * 192;
        oq[i] = (r < 576) ? f2bf(wqkv[i] * n3g[c]) : (unsigned short)0;
    } else if (i < 172032) {                // [256][192] bf16
        int j = i - 122880; int r = j / 192;
        oo[j] = (r < 192) ? f2bf(wout[j]) : (unsigned short)0;
    } else if (i < 319488) {                // [768][192] bf16
        int j = i - 172032; int c = j % 192;
        o1[j] = f2bf(wfc1[j] * n4g[c]);
    } else if (i < 417792) {                // [256][768] fp8, 2 elems/thread
        int j = i - 319488;                  // pair index over [256][384]
        int r = j / 384;
        float a = 0.f, b = 0.f;
        if (r < 192) { a = wfc2[2 * j]; b = wfc2[2 * j + 1]; }
        int pk = __builtin_amdgcn_cvt_pk_fp8_f32(a, b, 0, false);
        o2f8[j] = (unsigned short)pk;        // fp8 pairs
    }
}

// ---------------------------------------------------------------------------
// K0b: effective biases folding LN beta through the (raw) weights.
// ---------------------------------------------------------------------------
__global__ __launch_bounds__(256) void k_bias(const float* __restrict__ wqkv,
                                              const float* __restrict__ bqkv,
                                              const float* __restrict__ n3b,
                                              const float* __restrict__ wfc1,
                                              const float* __restrict__ bfc1,
                                              const float* __restrict__ n4b,
                                              float* __restrict__ beffq,
                                              float* __restrict__ beff1) {
    int wid = blockIdx.x * 4 + (threadIdx.x >> 6);
    int lane = threadIdx.x & 63;
    const float* wrow; const float* bb; float base; float* dst;
    if (wid < 576) { wrow = wqkv + (size_t)wid * 192; bb = n3b; base = bqkv[wid]; dst = beffq + wid; }
    else { int h = wid - 576; wrow = wfc1 + (size_t)h * 192; bb = n4b; base = bfc1[h]; dst = beff1 + h; }
    float s = wrow[lane] * bb[lane] + wrow[lane + 64] * bb[lane + 64]
            + wrow[lane + 128] * bb[lane + 128];
#pragma unroll
    for (int off = 32; off; off >>= 1) s += __shfl_xor(s, off);
    if (lane == 0) *dst = base + s;
}

// ---------------------------------------------------------------------------
// K1: LayerNorm(norm3) WITHOUT affine + window partition -> h bf16.
// ---------------------------------------------------------------------------
__global__ __launch_bounds__(256) void k_ln3(const float* __restrict__ x,
                                             unsigned short* __restrict__ h) {
    int w = threadIdx.x >> 6, lane = threadIdx.x & 63;
    int token = blockIdx.x * 4 + w;
    const float* xp = x + (size_t)token * 192;
    float v0 = xp[lane], v1 = xp[lane + 64], v2 = xp[lane + 128];
    float s = v0 + v1 + v2;
#pragma unroll
    for (int off = 32; off; off >>= 1) s += __shfl_xor(s, off);
    float mean = s * (1.f / 192.f);
    float d0 = v0 - mean, d1 = v1 - mean, d2 = v2 - mean;
    float q = d0 * d0 + d1 * d1 + d2 * d2;
#pragma unroll
    for (int off = 32; off; off >>= 1) q += __shfl_xor(q, off);
    float rs = rsqrtf(q * (1.f / 192.f) + 1e-5f);
    int b  = token / (8 * 96 * 96);
    int r0 = token - b * (8 * 96 * 96);
    int d  = r0 / (96 * 96);
    int r1 = r0 - d * (96 * 96);
    int hh = r1 / 96;
    int ww = r1 - hh * 96;
    int bp = b * 144 + (hh >> 3) * 12 + (ww >> 3);
    int l  = d * 64 + (hh & 7) * 8 + (ww & 7);
    unsigned short* hp = h + ((size_t)bp * 512 + l) * 192;
    hp[lane]       = f2bf(d0 * rs);
    hp[lane + 64]  = f2bf(d1 * rs);
    hp[lane + 128] = f2bf(d2 * rs);
}

// ---------------------------------------------------------------------------
// K5: LayerNorm(norm4) WITHOUT affine on bf16 ybf -> xn4 bf16.
// ---------------------------------------------------------------------------
__global__ __launch_bounds__(256) void k_ln4b(const unsigned short* __restrict__ yb,
                                              unsigned short* __restrict__ xn) {
    int sub = threadIdx.x >> 5, tl = threadIdx.x & 31;
    size_t row = (size_t)blockIdx.x * 8 + sub;
    const unsigned int* rp = reinterpret_cast<const unsigned int*>(yb + row * 192);
    float v[6];
#pragma unroll
    for (int j = 0; j < 3; j++) {
        unsigned int w = rp[tl + 32 * j];
        v[2 * j]     = bf2f((unsigned short)(w & 0xffffu));
        v[2 * j + 1] = bf2f((unsigned short)(w >> 16));
    }
    float s = v[0] + v[1] + v[2] + v[3] + v[4] + v[5];
#pragma unroll
    for (int off = 1; off < 32; off <<= 1) s += __shfl_xor(s, off);
    float mean = s * (1.f / 192.f);
    float q = 0.f;
#pragma unroll
    for (int j = 0; j < 6; j++) { v[j] -= mean; q += v[j] * v[j]; }
#pragma unroll
    for (int off = 1; off < 32; off <<= 1) q += __shfl_xor(q, off);
    float rs = rsqrtf(q * (1.f / 192.f) + 1e-5f);
    unsigned int* op = reinterpret_cast<unsigned int*>(xn + row * 192);
#pragma unroll
    for (int j = 0; j < 3; j++) {
        unsigned short lo = f2bf(v[2 * j]     * rs);
        unsigned short hi = f2bf(v[2 * j + 1] * rs);
        op[tl + 32 * j] = ((unsigned int)hi << 16) | lo;
    }
}

// ---------------------------------------------------------------------------
// K2: 128xBN GEMM (BN = NF*32), dbuf + counted-vmcnt, packed epilogues.
// EPI 0 (NF=4): qkv -> qk (q scaled) + vt
// EPI 1 (NF=3): out_proj + window-reverse + x residual -> ybf bf16
// EPI 2 (NF=4): fc1 + gelu_sig -> hidden fp8 (ld 768)
// ---------------------------------------------------------------------------
template <int EPI, int K, int NF>
__global__ __launch_bounds__(256) void k_gemm128(const unsigned short* __restrict__ A,
                                                 const unsigned short* __restrict__ Bw,
                                                 const float* __restrict__ bias,
                                                 unsigned short* __restrict__ outb,
                                                 unsigned short* __restrict__ vt,
                                                 const float* __restrict__ res,
                                                 unsigned char* __restrict__ outf8) {
    __shared__ unsigned short As[2][128 * 64];
    __shared__ unsigned short Bs[2][NF * 32 * 64];
    const int tid = threadIdx.x;
    const int nwg = gridDim.x * gridDim.y;
    const int flat = blockIdx.y * gridDim.x + blockIdx.x;
    const int swz = (flat & 7) * (nwg >> 3) + (flat >> 3);
    const int bx = swz % gridDim.x, by = swz / gridDim.x;
    const int row0 = by * 128, col0 = bx * (NF * 32);
    const int wv = tid >> 6, lane = tid & 63, lr = lane & 15, lg = lane >> 4;
    const int wr = wv >> 1, wc = wv & 1;
    const int sr = lane >> 3, sc = lane & 7;
    f32x4 acc[4][NF] = {};

    auto stage = [&](int t, int buf) {
        int k0 = t * 64;
#pragma unroll
        for (int i = 0; i < 4; i++) {
            int gq = wv * 4 + i;
            int r = gq * 8 + sr;
            int j = sc ^ (r & 7);
            gl_lds16(A + (size_t)(row0 + r) * K + k0 + j * 8, &As[buf][gq * 512]);
        }
#pragma unroll
        for (int i = 0; i < NF; i++) {
            int gq = wv * NF + i;
            int r = gq * 8 + sr;
            int j = sc ^ (r & 7);
            gl_lds16(Bw + (size_t)(col0 + r) * K + k0 + j * 8, &Bs[buf][gq * 512]);
        }
    };

    const int NT = K / 64;
    stage(0, 0);
    for (int t = 0; t < NT; ++t) {
        int cur = t & 1;
        if (t + 1 < NT) {
            stage(t + 1, cur ^ 1);
            if constexpr (NF == 4) asm volatile("s_waitcnt vmcnt(8)" ::: "memory");
            else                   asm volatile("s_waitcnt vmcnt(7)" ::: "memory");
        } else {
            asm volatile("s_waitcnt vmcnt(0)" ::: "memory");
        }
        __builtin_amdgcn_sched_barrier(0);
        __builtin_amdgcn_s_barrier();
        __builtin_amdgcn_sched_barrier(0);
#pragma unroll
        for (int kk = 0; kk < 64; kk += 32) {
            bf16x8 af[4], bf[NF];
#pragma unroll
            for (int m = 0; m < 4; m++) {
                int r = wr * 64 + m * 16 + lr;
                int j = ((kk >> 3) + lg) ^ (r & 7);
                af[m] = __builtin_bit_cast(bf16x8,
                    *reinterpret_cast<const u32x4*>(&As[cur][r * 64 + j * 8]));
            }
#pragma unroll
            for (int n = 0; n < NF; n++) {
                int r = wc * (NF * 16) + n * 16 + lr;
                int j = ((kk >> 3) + lg) ^ (r & 7);
                bf[n] = __builtin_bit_cast(bf16x8,
                    *reinterpret_cast<const u32x4*>(&Bs[cur][r * 64 + j * 8]));
            }
#pragma unroll
            for (int m = 0; m < 4; m++)
#pragma unroll
                for (int n = 0; n < NF; n++)
                    acc[m][n] = __builtin_amdgcn_mfma_f32_16x16x32_bf16(bf[n], af[m], acc[m][n], 0, 0, 0);
        }
        __builtin_amdgcn_sched_barrier(0);
        __builtin_amdgcn_s_barrier();
        __builtin_amdgcn_sched_barrier(0);
    }

#pragma unroll
    for (int m = 0; m < 4; m++) {
        const int arow = row0 + wr * 64 + m * 16 + lr;
        if constexpr (EPI == 0) {
#pragma unroll
            for (int n = 0; n < NF; n++) {
                const int colb = col0 + wc * (NF * 16) + n * 16 + lg * 4;
                if (colb < 384) {
                    f32x4 b4 = *reinterpret_cast<const f32x4*>(bias + colb);
                    float sc2 = (colb < 192) ? 0.1020620726159658f : 1.f;  // 1/sqrt(96) on q
                    u16x4 pk;
#pragma unroll
                    for (int rr = 0; rr < 4; rr++) pk[rr] = f2bf((acc[m][n][rr] + b4[rr]) * sc2);
                    *reinterpret_cast<u16x4*>(outb + (size_t)arow * 384 + colb) = pk;
                } else if (colb < 576) {
                    int head = (colb >= 480) ? 1 : 0;
                    int bp = arow >> 9, tok = arow & 511;
                    size_t vb = ((size_t)(bp * 2 + head) * 96 + (colb - 384 - head * 96)) * 512 + tok;
#pragma unroll
                    for (int rr = 0; rr < 4; rr++)
                        vt[vb + (size_t)rr * 512] = f2bf(acc[m][n][rr] + bias[colb + rr]);
                }
            }
        } else if constexpr (EPI == 1) {
            int bp = arow >> 9, l = arow & 511;
            int bb = bp / 144, p = bp - bb * 144;
            int hn = p / 12, wn = p - hn * 12;
            int dn = l >> 6, t_ = l & 63;
            size_t tok = ((size_t)((bb * 8 + dn) * 96 + hn * 8 + (t_ >> 3)) * 96 + wn * 8 + (t_ & 7));
#pragma unroll
            for (int n = 0; n < NF; n++) {
                const int colb = col0 + wc * (NF * 16) + n * 16 + lg * 4;   // < 192
                size_t idx = tok * 192 + colb;
                f32x4 r4 = *reinterpret_cast<const f32x4*>(res + idx);
                f32x4 b4 = *reinterpret_cast<const f32x4*>(bias + colb);
                u16x4 pk;
#pragma unroll
                for (int rr = 0; rr < 4; rr++) pk[rr] = f2bf(r4[rr] + acc[m][n][rr] + b4[rr]);
                *reinterpret_cast<u16x4*>(outb + idx) = pk;
            }
        } else {
#pragma unroll
            for (int n = 0; n < NF; n++) {
                const int colb = col0 + wc * (NF * 16) + n * 16 + lg * 4;   // < 768
                f32x4 b4 = *reinterpret_cast<const f32x4*>(bias + colb);
                float g0 = gelu_sig(acc[m][n][0] + b4[0]);
                float g1 = gelu_sig(acc[m][n][1] + b4[1]);
                float g2 = gelu_sig(acc[m][n][2] + b4[2]);
                float g3 = gelu_sig(acc[m][n][3] + b4[3]);
                *reinterpret_cast<unsigned int*>(outf8 + (size_t)arow * 768 + colb) =
                    pk_fp8x4(g0, g1, g2, g3);
            }
        }
    }
}

// ---------------------------------------------------------------------------
// K3: block-causal attention (unchanged).
// ---------------------------------------------------------------------------
__global__ __launch_bounds__(512) void k_attn(const unsigned short* __restrict__ qk,
                                              const unsigned short* __restrict__ vt,
                                              unsigned short* __restrict__ aout) {
    __shared__ unsigned short Ks[64][104];
    __shared__ unsigned short Vs[96][72];
    __shared__ unsigned short Ps[8][16][72];

    int bid = (blockIdx.x & 7) * 288 + (blockIdx.x >> 3);
    int bp = bid >> 3, rest = bid & 7, head = rest >> 2, pr = rest & 3;
    int tid = threadIdx.x, wv = tid >> 6, lane = tid & 63;
    int lr = lane & 15, lg = lane >> 4;
    int wq = wv & 3, wt = wv >> 2;
    int nk = 2 * pr + 2;

    size_t qrow0 = (size_t)bp * 512 + (size_t)(2 * pr + wt) * 64;
    const unsigned short* vbase = vt + (size_t)(bp * 2 + head) * 96 * 512;
    size_t krowb = (size_t)bp * 512;

    bf16x8 qf[3];
    {
        const unsigned short* qp = qk + (qrow0 + wq * 16 + lr) * 384 + head * 96 + lg * 8;
#pragma unroll
        for (int ks = 0; ks < 3; ks++)
            qf[ks] = __builtin_bit_cast(bf16x8, *reinterpret_cast<const u32x4*>(qp + ks * 32));
    }

    f32x4 o[6] = {};
    float m_ = -1e30f, lsum = 0.f;

    u32x4 sreg[3];
    auto issue = [&](int dnk) {
#pragma unroll
        for (int i = 0; i < 3; i++) {
            int c = tid + i * 512;
            if (c < 768) {
                int r = c / 12, cc = c - r * 12;
                sreg[i] = *reinterpret_cast<const u32x4*>(
                    qk + (krowb + dnk * 64 + r) * 384 + 192 + head * 96 + cc * 8);
            } else {
                int c2 = c - 768; int d = c2 >> 3, tb = c2 & 7;
                sreg[i] = *reinterpret_cast<const u32x4*>(
                    vbase + (size_t)d * 512 + dnk * 64 + tb * 8);
            }
        }
    };
    auto commit = [&]() {
#pragma unroll
        for (int i = 0; i < 3; i++) {
            int c = tid + i * 512;
            if (c < 768) {
                int r = c / 12, cc = c - r * 12;
                *reinterpret_cast<u32x4*>(&Ks[r][cc * 8]) = sreg[i];
            } else {
                int c2 = c - 768; int d = c2 >> 3, tb = c2 & 7;
                *reinterpret_cast<u32x4*>(&Vs[d][tb * 8]) = sreg[i];
            }
        }
    };

    issue(0);
    for (int dnk = 0; dnk < nk; ++dnk) {
        commit();
        __syncthreads();
        if (dnk + 1 < nk) issue(dnk + 1);
        if (wt == 1 || dnk < nk - 1) {
            f32x4 st[4] = {};
#pragma unroll
            for (int ks = 0; ks < 3; ks++) {
#pragma unroll
                for (int ct = 0; ct < 4; ct++) {
                    bf16x8 kf = __builtin_bit_cast(bf16x8,
                        *reinterpret_cast<const u32x4*>(&Ks[ct * 16 + lr][ks * 32 + lg * 8]));
                    st[ct] = __builtin_amdgcn_mfma_f32_16x16x32_bf16(kf, qf[ks], st[ct], 0, 0, 0);
                }
            }
            float mx = st[0][0];
#pragma unroll
            for (int ct = 0; ct < 4; ct++)
#pragma unroll
                for (int rr = 0; rr < 4; rr++) mx = fmaxf(mx, st[ct][rr]);
            mx = fmaxf(mx, __shfl_xor(mx, 16));
            mx = fmaxf(mx, __shfl_xor(mx, 32));
            float mnew = fmaxf(m_, mx);
            float corr = __expf(m_ - mnew);
            m_ = mnew;
            float ps = 0.f;
#pragma unroll
            for (int ct = 0; ct < 4; ct++) {
                u16x4 pk;
#pragma unroll
                for (int rr = 0; rr < 4; rr++) {
                    float pv = __expf(st[ct][rr] - mnew);
                    ps += pv;
                    pk[rr] = f2bf(pv);
                }
                *reinterpret_cast<u16x4*>(&Ps[wv][lr][ct * 16 + lg * 4]) = pk;
            }
            ps += __shfl_xor(ps, 16);
            ps += __shfl_xor(ps, 32);
            lsum = lsum * corr + ps;
#pragma unroll
            for (int rr = 0; rr < 4; rr++) {
                float cr = __shfl(corr, (lane & 48) | (lg * 4 + rr));
#pragma unroll
                for (int nf = 0; nf < 6; nf++) o[nf][rr] *= cr;
            }
#pragma unroll
            for (int kk = 0; kk < 2; kk++) {
                bf16x8 pf = __builtin_bit_cast(bf16x8,
                    *reinterpret_cast<const u32x4*>(&Ps[wv][lr][kk * 32 + lg * 8]));
#pragma unroll
                for (int nf = 0; nf < 6; nf++) {
                    bf16x8 vf = __builtin_bit_cast(bf16x8,
                        *reinterpret_cast<const u32x4*>(&Vs[nf * 16 + lr][kk * 32 + lg * 8]));
                    o[nf] = __builtin_amdgcn_mfma_f32_16x16x32_bf16(pf, vf, o[nf], 0, 0, 0);
                }
            }
        }
        __syncthreads();
    }

#pragma unroll
    for (int rr = 0; rr < 4; rr++) {
        float li = __shfl(lsum, (lane & 48) | (lg * 4 + rr));
        float inv = 1.f / li;
        size_t row = qrow0 + wq * 16 + lg * 4 + rr;
#pragma unroll
        for (int nf = 0; nf < 6; nf++)
            aout[row * 192 + head * 96 + nf * 16 + lr] = f2bf(o[nf][rr] * inv);
    }
}

// ---------------------------------------------------------------------------
// K6: fc2 as fp8 x fp8 GEMM: out = hidden(fp8) @ w2(fp8)^T + b2 + ybf.
// 128x96 tile (NF=3), K=768 (12 k-tiles), LDS 32 KB. (unchanged from R14)
// ---------------------------------------------------------------------------
__global__ __launch_bounds__(256) void k_fc2(const unsigned char* __restrict__ hid,
                                             const unsigned char* __restrict__ w2,
                                             const float* __restrict__ b2,
                                             const unsigned short* __restrict__ ybf,
                                             float* __restrict__ out) {
    __shared__ unsigned char As[2][128 * 64];    // 16 KB
    __shared__ unsigned char Bs[2][128 * 64];    // 16 KB
    const int tid = threadIdx.x;
    const int nwg = gridDim.x * gridDim.y;
    const int flat = blockIdx.y * gridDim.x + blockIdx.x;
    const int swz = (flat & 7) * (nwg >> 3) + (flat >> 3);
    const int bx = swz % gridDim.x, by = swz / gridDim.x;
    const int row0 = by * 128, col0 = bx * 96;
    const int wv = tid >> 6, lane = tid & 63, lr = lane & 15, lg = lane >> 4;
    const int wr = wv >> 1, wc = wv & 1;
    const int sr4 = lane >> 2, sc4 = lane & 3;   // 16 rows x 4 chunks per 1KB group
    f32x4 acc[4][3] = {};

    auto stage = [&](int t, int buf) {
        int k0 = t * 64;
#pragma unroll
        for (int i = 0; i < 2; i++) {
            int g = wv * 2 + i;                  // 8 groups of 16 rows
            int r = g * 16 + sr4;
            int j = sc4 ^ (r & 3);
            gl_lds16(hid + (size_t)(row0 + r) * 768 + k0 + j * 16, &As[buf][g * 1024]);
        }
#pragma unroll
        for (int i = 0; i < 2; i++) {
            int g = wv * 2 + i;
            int r = g * 16 + sr4;
            int j = sc4 ^ (r & 3);
            gl_lds16(w2 + (size_t)(col0 + r) * 768 + k0 + j * 16, &Bs[buf][g * 1024]);
        }
    };

    stage(0, 0);
    for (int t = 0; t < 12; ++t) {
        int cur = t & 1;
        if (t + 1 < 12) {
            stage(t + 1, cur ^ 1);
            asm volatile("s_waitcnt vmcnt(4)" ::: "memory");
        } else {
            asm volatile("s_waitcnt vmcnt(0)" ::: "memory");
        }
        __builtin_amdgcn_sched_barrier(0);
        __builtin_amdgcn_s_barrier();
        __builtin_amdgcn_sched_barrier(0);
#pragma unroll
        for (int kk = 0; kk < 2; kk++) {
            const int cc = kk * 2 + (lg >> 1);   // 16B chunk index of this frag
            const int off = (lg & 1) * 8;
            unsigned long long af[4], bfr[3];
#pragma unroll
            for (int m = 0; m < 4; m++) {
                int r = wr * 64 + m * 16 + lr;
                int j = cc ^ (r & 3);
                af[m] = *reinterpret_cast<const unsigned long long*>(
                    &As[cur][r * 64 + j * 16 + off]);
            }
#pragma unroll
            for (int n = 0; n < 3; n++) {
                int r = wc * 48 + n * 16 + lr;
                int j = cc ^ (r & 3);
                bfr[n] = *reinterpret_cast<const unsigned long long*>(
                    &Bs[cur][r * 64 + j * 16 + off]);
            }
#pragma unroll
            for (int m = 0; m < 4; m++)
#pragma unroll
                for (int n = 0; n < 3; n++)
                    acc[m][n] = mfma_fp8(bfr[n], af[m], acc[m][n]);
        }
        __builtin_amdgcn_sched_barrier(0);
        __builtin_amdgcn_s_barrier();
        __builtin_amdgcn_sched_barrier(0);
    }

    // epilogue: bias + ybf residual -> fp32 out
#pragma unroll
    for (int m = 0; m < 4; m++) {
        const int arow = row0 + wr * 64 + m * 16 + lr;
#pragma unroll
        for (int n = 0; n < 3; n++) {
            const int colb = col0 + wc * 48 + n * 16 + lg * 4;   // < 192
            size_t idx = (size_t)arow * 192 + colb;
            f32x4 b4 = *reinterpret_cast<const f32x4*>(b2 + colb);
            u16x4 rb = *reinterpret_cast<const u16x4*>(ybf + idx);
            f32x4 o4;
#pragma unroll
            for (int rr = 0; rr < 4; rr++) o4[rr] = bf2f(rb[rr]) + acc[m][n][rr] + b4[rr];
            *reinterpret_cast<f32x4*>(out + idx) = o4;
        }
    }
}

// ---------------------------------------------------------------------------
// Launcher. ws arena (~341 MB):
//   [0, 113.2M)        phase A: qk bf16 ; phase B: hidden fp8 [147456][768]
//   [113.2M, 169.9M)   vt bf16
//   [169.9M, 226.5M)   attn bf16
//   [226.5M, 283.1M)   ybf bf16
//   [283.1M, 339.7M)   phase A: h bf16 (ln3 out) ; phase B: xn4 (aliases h)
//   [339.7M, ~341M)    weights (wq/wo/w1 bf16 gamma-folded, w2 fp8) + biases
// d_out written only by k_fc2 (fully rewritten each call => replay safe).
// ---------------------------------------------------------------------------
extern "C" void kernel_launch(void* const* d_in, const int* in_sizes, int n_in,
                              void* d_out, int out_size, void* d_ws, size_t ws_size,
                              hipStream_t stream) {
    const float* x    = (const float*)d_in[0];
    const float* n3g  = (const float*)d_in[1];
    const float* n3b  = (const float*)d_in[2];
    const float* wqkv = (const float*)d_in[3];
    const float* bqkv = (const float*)d_in[4];
    const float* wout = (const float*)d_in[5];
    const float* bout = (const float*)d_in[6];
    const float* n4g  = (const float*)d_in[7];
    const float* n4b  = (const float*)d_in[8];
    const float* wfc1 = (const float*)d_in[9];
    const float* bfc1 = (const float*)d_in[10];
    const float* wfc2 = (const float*)d_in[11];
    const float* bfc2 = (const float*)d_in[12];
    float* out = (float*)d_out;

    char* ws = (char*)d_ws;
    unsigned short* qk     = (unsigned short*)(ws + 0);
    unsigned char*  hidden = (unsigned char*)(ws + 0);            // aliases qk (dead)
    unsigned short* vt     = (unsigned short*)(ws + 113246208);
    unsigned short* attn   = (unsigned short*)(ws + 169869312);
    unsigned short* ybf    = (unsigned short*)(ws + 226492416);
    unsigned short* h      = (unsigned short*)(ws + 283115520);
    unsigned short* xn4    = (unsigned short*)(ws + 283115520);   // aliases h (dead)
    unsigned short* wq_bf  = (unsigned short*)(ws + 339738624);
    unsigned short* wo_bf  = (unsigned short*)(ws + 339984384);
    unsigned short* w1_bf  = (unsigned short*)(ws + 340082688);
    unsigned short* w2_f8p = (unsigned short*)(ws + 340377600);   // fp8 pairs
    unsigned char*  w2_f8  = (unsigned char*)(ws + 340377600);
    float*          beffq  = (float*)(ws + 340574208);
    float*          beff1  = (float*)(ws + 340576512);

    k_wconv<<<1632, 256, 0, stream>>>(wqkv, wout, wfc1, wfc2, n3g, n4g, wq_bf, wo_bf, w1_bf, w2_f8p);
    k_bias<<<336, 256, 0, stream>>>(wqkv, bqkv, n3b, wfc1, bfc1, n4b, beffq, beff1);
    k_ln3<<<36864, 256, 0, stream>>>(x, h);
    k_gemm128<0, 192, 4><<<dim3(5, 1152), 256, 0, stream>>>(h, wq_bf, beffq, qk, vt, nullptr, nullptr);
    k_attn<<<2304, 512, 0, stream>>>(qk, vt, attn);
    k_gemm128<1, 192, 3><<<dim3(2, 1152), 256, 0, stream>>>(attn, wo_bf, bout, ybf, nullptr, x, nullptr);
    k_ln4b<<<18432, 256, 0, stream>>>(ybf, xn4);
    k_gemm128<2, 192, 4><<<dim3(6, 1152), 256, 0, stream>>>(xn4, w1_bf, beff1, nullptr, nullptr, nullptr, hidden);
    k_fc2<<<dim3(2, 1152), 256, 0, stream>>>(hidden, w2_f8, bfc2, ybf, out);
}